// Round 11
// baseline (11225.317 us; speedup 1.0000x reference)
//
#include <hip/hip_runtime.h>

#define Bsz  4
#define Lsz  4096
#define Csz  1024
#define NHsz 16
#define CSsz 16
#define HFsz 64
#define HF4sz 256
#define NCsz 256

typedef __attribute__((ext_vector_type(8))) short  bhalf8;
typedef __attribute__((ext_vector_type(4))) float  floatx4;

// ---------------------------------------------------------------------------
// fp32 -> bf16 helpers.  tsplit: trunc-hi + RNE-lo (x ~= h+l, |err|~2^-16|x|).
// ---------------------------------------------------------------------------
__device__ __forceinline__ unsigned short bf_rne(float x) {
  const unsigned u = __float_as_uint(x);
  return (unsigned short)((u + 0x7fffu + ((u >> 16) & 1u)) >> 16);
}
__device__ __forceinline__ void split_rne(float x, unsigned short& h, unsigned short& l) {
  h = bf_rne(x);
  const float hf = __uint_as_float((unsigned)h << 16);
  l = bf_rne(x - hf);
}
__device__ __forceinline__ void tsplit(float x, unsigned short& h, unsigned short& l) {
  const unsigned u = __float_as_uint(x);
  h = (unsigned short)(u >> 16);
  const float r = x - __uint_as_float(u & 0xffff0000u);
  l = bf_rne(r);
}
__device__ __forceinline__ void split_frag8(const float* __restrict__ x,
                                            bhalf8& h, bhalf8& l) {
#pragma unroll
  for (int e = 0; e < 8; ++e) {
    unsigned short hs, ls;
    tsplit(x[e], hs, ls);
    h[e] = (short)hs; l[e] = (short)ls;
  }
}
__device__ __forceinline__ float recon2(unsigned short h, unsigned short l) {
  return __uint_as_float((unsigned)h << 16) + __uint_as_float((unsigned)l << 16);
}

#define MFMA3(acc, ah, al, bh, bl)                                            \
  acc = __builtin_amdgcn_mfma_f32_16x16x32_bf16(ah, bh, acc, 0, 0, 0);        \
  acc = __builtin_amdgcn_mfma_f32_16x16x32_bf16(ah, bl, acc, 0, 0, 0);        \
  acc = __builtin_amdgcn_mfma_f32_16x16x32_bf16(al, bh, acc, 0, 0, 0);

// sW2 block-swizzled index: [256 k][64 m] ushort, 16B blocks XOR'd by
// swz(k) = ((k>>3)^k)&7.  Same formula at init-write, P7-rebuild, P4-read.
#define W2IDX(k, mm) ((k) * 64 + (((((mm) >> 3) ^ ((k) >> 3) ^ (k)) & 7) << 3) + ((mm) & 7))

// ---------------------------------------------------------------------------
// bulk fp32 -> split-bf16 (hi[], lo[]) for the big GEMMs (RNE split).
// ---------------------------------------------------------------------------
__global__ __launch_bounds__(256)
void split32(const float* __restrict__ in, unsigned short* __restrict__ hi,
             unsigned short* __restrict__ lo)
{
  const int i = (blockIdx.x * 256 + threadIdx.x) * 4;
  const float4 v = *(const float4*)&in[i];
  ushort4 h, l;
  split_rne(v.x, h.x, l.x);
  split_rne(v.y, h.y, l.y);
  split_rne(v.z, h.z, l.z);
  split_rne(v.w, h.w, l.w);
  *(ushort4*)&hi[i] = h;
  *(ushort4*)&lo[i] = l;
}

// ---------------------------------------------------------------------------
// MFMA GEMM (validated round 9): C = A@B, A pre-split, B fp32 inline-split.
// ---------------------------------------------------------------------------
__global__ __launch_bounds__(256)
void gemm_mfma(const unsigned short* __restrict__ Ahi,
               const unsigned short* __restrict__ Alo,
               const float* __restrict__ Bm,
               float* __restrict__ Cm, int M, int N, int K)
{
  __shared__ unsigned short sAh[128 * 40];
  __shared__ unsigned short sAl[128 * 40];
  __shared__ unsigned short sBh[128 * 40];
  __shared__ unsigned short sBl[128 * 40];

  const int t    = threadIdx.x;
  const int lane = t & 63, w = t >> 6;
  const int wr   = (w >> 1) * 64, wc = (w & 1) * 64;
  const int row0 = blockIdx.y * 128, col0 = blockIdx.x * 128;
  const int fr   = lane & 15, fk = (lane >> 4) * 8;

  floatx4 acc[4][4];
#pragma unroll
  for (int mi = 0; mi < 4; ++mi)
#pragma unroll
    for (int ni = 0; ni < 4; ++ni) acc[mi][ni] = (floatx4){0.f, 0.f, 0.f, 0.f};

  const int arow = t >> 1, akg = (t & 1) * 16;
  const int bc4  = (t & 31) * 4, bk4 = (t >> 5) * 4;

  for (int k0 = 0; k0 < K; k0 += 32) {
    {
      const size_t ga = (size_t)(row0 + arow) * K + k0 + akg;
      const bhalf8 h0 = *(const bhalf8*)&Ahi[ga];
      const bhalf8 h1 = *(const bhalf8*)&Ahi[ga + 8];
      const bhalf8 l0 = *(const bhalf8*)&Alo[ga];
      const bhalf8 l1 = *(const bhalf8*)&Alo[ga + 8];
      *(bhalf8*)&sAh[arow * 40 + akg]     = h0;
      *(bhalf8*)&sAh[arow * 40 + akg + 8] = h1;
      *(bhalf8*)&sAl[arow * 40 + akg]     = l0;
      *(bhalf8*)&sAl[arow * 40 + akg + 8] = l1;
    }
    {
      const float4 r0 = *(const float4*)&Bm[(size_t)(k0 + bk4 + 0) * N + col0 + bc4];
      const float4 r1 = *(const float4*)&Bm[(size_t)(k0 + bk4 + 1) * N + col0 + bc4];
      const float4 r2 = *(const float4*)&Bm[(size_t)(k0 + bk4 + 2) * N + col0 + bc4];
      const float4 r3 = *(const float4*)&Bm[(size_t)(k0 + bk4 + 3) * N + col0 + bc4];
#define STORE_BCOL(v0, v1, v2, v3, c) do {                                   \
      unsigned short h0_, h1_, h2_, h3_, l0_, l1_, l2_, l3_;                 \
      split_rne(v0, h0_, l0_); split_rne(v1, h1_, l1_);                      \
      split_rne(v2, h2_, l2_); split_rne(v3, h3_, l3_);                      \
      const int off_ = (bc4 + (c)) * 40 + bk4;                               \
      *(unsigned*)&sBh[off_]     = (unsigned)h0_ | ((unsigned)h1_ << 16);    \
      *(unsigned*)&sBh[off_ + 2] = (unsigned)h2_ | ((unsigned)h3_ << 16);    \
      *(unsigned*)&sBl[off_]     = (unsigned)l0_ | ((unsigned)l1_ << 16);    \
      *(unsigned*)&sBl[off_ + 2] = (unsigned)l2_ | ((unsigned)l3_ << 16);    \
    } while (0)
      STORE_BCOL(r0.x, r1.x, r2.x, r3.x, 0);
      STORE_BCOL(r0.y, r1.y, r2.y, r3.y, 1);
      STORE_BCOL(r0.z, r1.z, r2.z, r3.z, 2);
      STORE_BCOL(r0.w, r1.w, r2.w, r3.w, 3);
#undef STORE_BCOL
    }
    __syncthreads();

    bhalf8 ah[4], al[4];
#pragma unroll
    for (int mi = 0; mi < 4; ++mi) {
      ah[mi] = *(const bhalf8*)&sAh[(wr + mi * 16 + fr) * 40 + fk];
      al[mi] = *(const bhalf8*)&sAl[(wr + mi * 16 + fr) * 40 + fk];
    }
#pragma unroll
    for (int ni = 0; ni < 4; ++ni) {
      const bhalf8 bh = *(const bhalf8*)&sBh[(wc + ni * 16 + fr) * 40 + fk];
      const bhalf8 bl = *(const bhalf8*)&sBl[(wc + ni * 16 + fr) * 40 + fk];
#pragma unroll
      for (int mi = 0; mi < 4; ++mi) {
        acc[mi][ni] = __builtin_amdgcn_mfma_f32_16x16x32_bf16(ah[mi], bh, acc[mi][ni], 0, 0, 0);
        acc[mi][ni] = __builtin_amdgcn_mfma_f32_16x16x32_bf16(ah[mi], bl, acc[mi][ni], 0, 0, 0);
        acc[mi][ni] = __builtin_amdgcn_mfma_f32_16x16x32_bf16(al[mi], bh, acc[mi][ni], 0, 0, 0);
      }
    }
    __syncthreads();
  }

  const int er = (lane >> 4) * 4;
#pragma unroll
  for (int mi = 0; mi < 4; ++mi)
#pragma unroll
    for (int ni = 0; ni < 4; ++ni) {
      const size_t base = (size_t)(row0 + wr + mi * 16 + er) * N + col0 + wc + ni * 16 + fr;
#pragma unroll
      for (int j = 0; j < 4; ++j)
        Cm[base + (size_t)j * N] = acc[mi][ni][j];
    }
}

// ---------------------------------------------------------------------------
// ilr -> coeff table (unchanged)
// ---------------------------------------------------------------------------
__global__ __launch_bounds__(256)
void ilr_coeff(const float* __restrict__ H, const float* __restrict__ Wil,
               const float* __restrict__ bil, float* __restrict__ coeff)
{
  __shared__ float sRow[4][1024];
  __shared__ float sP[4][16][17];
  const int t = threadIdx.x;
  const size_t r0 = (size_t)blockIdx.x * 4;
  for (int rr = 0; rr < 4; ++rr)
    for (int c = t; c < 1024; c += 256)
      sRow[rr][c] = H[(r0 + rr) * 1024 + c];
  __syncthreads();
  const int hh = t & 15, sl = t >> 4;
  for (int rr = 0; rr < 4; ++rr) {
    float acc = 0.f;
    for (int kk = 0; kk < 64; ++kk)
      acc += sRow[rr][sl * 64 + kk] * Wil[(sl * 64 + kk) * 16 + hh];
    sP[rr][sl][hh] = acc;
  }
  __syncthreads();
  if (t < 64) {
    const int rr = t >> 4, h2 = t & 15;
    float s = 0.f;
    for (int sl2 = 0; sl2 < 16; ++sl2) s += sP[rr][sl2][h2];
    s += bil[h2];
    const float sig = 1.f / (1.f + expf(-s));
    const int r  = (int)(r0 + rr);
    const int b  = r >> 12, l = r & 4095, nc = l >> 4, cs = l & 15;
    coeff[((b * 16 + h2) * NCsz + nc) * CSsz + cs] = sig / ((float)(cs + 1) * 64.0f);
  }
}

// ---------------------------------------------------------------------------
// TTT scan v13 — MFMA, pressure/conflict-tuned (round-10 post-mortem).
// Structure = v12 with:
//  * z1bp MFMA moved P1'->P4 (A was idle; zba spans 1 barrier not 4)
//  * W2 update i-halved (cg[8]); g1 per-r with hoisted g2 frags
//  * sZ1t fg-XOR 16B blocks; sXBt row-major [16][68]; sW2 [256][64]+W2IDX
//  * XA prefetch in B's idle P5
// 5 barriers/chunk; LDS 154,816 B; est peak live regs ~100-115 (no spill).
// ---------------------------------------------------------------------------
__global__ __launch_bounds__(512)
void ttt_scan(const float* __restrict__ XA, const float* __restrict__ XBuf,
              const float* __restrict__ XCbuf, const float* __restrict__ coeff,
              const float* __restrict__ W1g, const float* __restrict__ W2g,
              float* __restrict__ Out)
{
  __shared__ __attribute__((aligned(16))) unsigned short sW2h[256 * 64]; // 32768
  __shared__ __attribute__((aligned(16))) unsigned short sW2l[256 * 64]; // 32768
  __shared__ __attribute__((aligned(16))) unsigned short sZ1h[16 * 264]; // 8448
  __shared__ __attribute__((aligned(16))) unsigned short sZ1l[16 * 264];
  __shared__ __attribute__((aligned(16))) unsigned short sZbh[16 * 264];
  __shared__ __attribute__((aligned(16))) unsigned short sZbl[16 * 264];
  __shared__ __attribute__((aligned(16))) float sZ1t[256 * 20];          // 20480
  __shared__ __attribute__((aligned(16))) float sG1 [256 * 20];          // 20480
  __shared__ __attribute__((aligned(16))) unsigned short sg2h[16 * 72];  // 2304
  __shared__ __attribute__((aligned(16))) unsigned short sg2l[16 * 72];
  __shared__ __attribute__((aligned(16))) float sXBt[16 * 68];           // 4352
  __shared__ __attribute__((aligned(16))) float sA1 [16 * 17];           // 1088
  __shared__ __attribute__((aligned(16))) float sA2p[4 * 16 * 17];       // 4352
  __shared__ __attribute__((aligned(16))) float sCo [2 * 16];            // 128

  const int t    = threadIdx.x;
  const int bh   = blockIdx.x;            // 0..63
  const int b    = bh >> 4, h = bh & 15;
  const bool isA = (t < 256);
  const int lane = t & 63;
  const int fr   = lane & 15, fg = lane >> 4;
  const int w    = t >> 6;                // A: 0..3
  const int tb   = t - 256;               // B local
  const int wb   = (t >> 6) & 3;          // B: 0..3
  const int m    = 16 * wb + fr;          // B: W2 col

  float w1m[64];   // A masters (frag layout: [tt*16 + ks*8 + e])
  float w2m[64];   // B masters (frag layout: [ks*8 + e])
  floatx4 zba[4];  // A: z1bp D-frags (P4 -> P5 only)
  floatx4 zb2;     // B: Z2b D-frag  (P6 -> P7)
  float xar[4];    // B: XA prefetch

  const float* W1h = W1g + h * HFsz * HF4sz;
  const float* W2h = W2g + h * HF4sz * HFsz;
  if (isA) {
#pragma unroll
    for (int tt = 0; tt < 4; ++tt)
#pragma unroll
      for (int ks = 0; ks < 2; ++ks)
#pragma unroll
        for (int e = 0; e < 8; ++e)
          w1m[tt * 16 + ks * 8 + e] = W1h[(32 * ks + 8 * fg + e) * 256 + (64 * w + 16 * tt + fr)];
  } else {
#pragma unroll
    for (int ks = 0; ks < 8; ++ks)
#pragma unroll
      for (int e = 0; e < 8; ++e)
        w2m[ks * 8 + e] = W2h[(32 * ks + 8 * fg + e) * 64 + m];
#pragma unroll
    for (int ks = 0; ks < 8; ++ks)
#pragma unroll
      for (int e = 0; e < 8; ++e) {
        const int k = 32 * ks + 8 * fg + e;
        unsigned short hs, ls;
        tsplit(w2m[ks * 8 + e], hs, ls);
        const int idx = W2IDX(k, m);
        sW2h[idx] = hs;
        sW2l[idx] = ls;
      }
    const int cb0 = (b * Lsz) * Csz + h * HFsz;
#pragma unroll
    for (int j = 0; j < 4; ++j)
      xar[j] = XA[cb0 + (4 * fg + j) * 1024 + m];
  }
  __syncthreads();

#pragma unroll 1
  for (int nc = 0; nc < NCsz; ++nc) {
    const int cur = nc & 1;
    const int cb  = (b * Lsz + nc * CSsz) * Csz + h * HFsz;
    const int nc1 = (nc + 1) & (NCsz - 1);
    const int cb1 = (b * Lsz + nc1 * CSsz) * Csz + h * HFsz;
    const float* __restrict__ xbG = XBuf  + cb;
    const float* __restrict__ xcG = XCbuf + cb;

    // ================= P1': A: Z1 MFMA | B: Attn1 ========================
    if (isA) {
      if (t < 16) sCo[cur * 16 + t] = coeff[(bh * NCsz + nc) * CSsz + t];
      const float* __restrict__ xbp = xbG + fr * 1024 + 8 * fg;
      float xv[8];
      bhalf8 xh0, xl0, xh1, xl1;
      *(float4*)&xv[0] = *(const float4*)&xbp[0];
      *(float4*)&xv[4] = *(const float4*)&xbp[4];
      split_frag8(xv, xh0, xl0);
      *(float4*)&xv[0] = *(const float4*)&xbp[32];
      *(float4*)&xv[4] = *(const float4*)&xbp[36];
      split_frag8(xv, xh1, xl1);
#pragma unroll
      for (int tt = 0; tt < 4; ++tt) {
        bhalf8 wh, wl;
        floatx4 acc = (floatx4){0.f, 0.f, 0.f, 0.f};
        split_frag8(&w1m[tt * 16], wh, wl);
        MFMA3(acc, xh0, xl0, wh, wl);
        split_frag8(&w1m[tt * 16 + 8], wh, wl);
        MFMA3(acc, xh1, xl1, wh, wl);
        const int n = 64 * w + 16 * tt + fr;
#pragma unroll
        for (int j = 0; j < 4; ++j) {
          const int i = 4 * fg + j;
          unsigned short hs, ls; tsplit(acc[j], hs, ls);
          sZ1h[i * 264 + n] = hs;
          sZ1l[i * 264 + n] = ls;
        }
        const int rotn = (n >> 3) & 3;
        *(float4*)&sZ1t[n * 20 + ((fg ^ rotn) << 2)] = *(float4*)&acc;
      }
    } else {
      const int ia = tb >> 4, ja = tb & 15;
      float a0 = 0.f, a1 = 0.f;
      if (ja <= ia) {
#pragma unroll
        for (int k = 0; k < 64; k += 8) {
          const float4 c0 = *(const float4*)&xcG[ia * 1024 + k];
          const float4 b0 = *(const float4*)&xbG[ja * 1024 + k];
          const float4 c1 = *(const float4*)&xcG[ia * 1024 + k + 4];
          const float4 b1 = *(const float4*)&xbG[ja * 1024 + k + 4];
          a0 = fmaf(c0.w, b0.w, fmaf(c0.z, b0.z, fmaf(c0.y, b0.y, fmaf(c0.x, b0.x, a0))));
          a1 = fmaf(c1.w, b1.w, fmaf(c1.z, b1.z, fmaf(c1.y, b1.y, fmaf(c1.x, b1.x, a1))));
        }
      }
      sA1[ia * 17 + ja] = a0 + a1;   // 0 on upper triangle
    }
    __syncthreads();

    // ================= P2': B: Z2 + g2 | A: XBt stage ====================
    if (!isA) {
      floatx4 z2a = (floatx4){0.f, 0.f, 0.f, 0.f};
#pragma unroll
      for (int ks = 0; ks < 8; ++ks) {
        const bhalf8 ah = *(const bhalf8*)&sZ1h[fr * 264 + 32 * ks + 8 * fg];
        const bhalf8 al = *(const bhalf8*)&sZ1l[fr * 264 + 32 * ks + 8 * fg];
        bhalf8 wh, wl; split_frag8(&w2m[ks * 8], wh, wl);
        MFMA3(z2a, ah, al, wh, wl);
      }
#pragma unroll
      for (int j = 0; j < 4; ++j) {
        const int i = 4 * fg + j;
        const float g2v = z2a[j] - xar[j];
        unsigned short hs, ls; tsplit(g2v, hs, ls);
        sg2h[i * 72 + m] = hs;
        sg2l[i * 72 + m] = ls;
      }
    } else {
      const int ir = t >> 4, k4 = (t & 15) * 4;
      *(float4*)&sXBt[ir * 68 + k4] = *(const float4*)&xbG[ir * 1024 + k4];
    }
    __syncthreads();

    // ========= P4: B: g1 MFMA -> sG1 | A: z1bp MFMA -> zba regs ==========
    if (!isA) {
      const bhalf8 gh0 = *(const bhalf8*)&sg2h[fr * 72 + 8 * fg];
      const bhalf8 gl0 = *(const bhalf8*)&sg2l[fr * 72 + 8 * fg];
      const bhalf8 gh1 = *(const bhalf8*)&sg2h[fr * 72 + 32 + 8 * fg];
      const bhalf8 gl1 = *(const bhalf8*)&sg2l[fr * 72 + 32 + 8 * fg];
#pragma unroll
      for (int r = 0; r < 4; ++r) {
        const int rt  = 4 * wb + r;
        const int row = 16 * rt + fr;
        const int swzr = ((row >> 3) ^ row) & 7;
        floatx4 acc = (floatx4){0.f, 0.f, 0.f, 0.f};
        {
          const int pb = fg ^ swzr;                       // ks2 = 0
          const bhalf8 ah = *(const bhalf8*)&sW2h[row * 64 + (pb << 3)];
          const bhalf8 al = *(const bhalf8*)&sW2l[row * 64 + (pb << 3)];
          MFMA3(acc, ah, al, gh0, gl0);
        }
        {
          const int pb = (4 + fg) ^ swzr;                 // ks2 = 1
          const bhalf8 ah = *(const bhalf8*)&sW2h[row * 64 + (pb << 3)];
          const bhalf8 al = *(const bhalf8*)&sW2l[row * 64 + (pb << 3)];
          MFMA3(acc, ah, al, gh1, gl1);
        }
#pragma unroll
        for (int j = 0; j < 4; ++j)
          sG1[(16 * rt + 4 * fg + j) * 20 + fr] = acc[j];
      }
    } else {
      const float* __restrict__ xcp = xcG + fr * 1024 + 8 * fg;
      float xv[8];
      bhalf8 xh0, xl0, xh1, xl1;
      *(float4*)&xv[0] = *(const float4*)&xcp[0];
      *(float4*)&xv[4] = *(const float4*)&xcp[4];
      split_frag8(xv, xh0, xl0);
      *(float4*)&xv[0] = *(const float4*)&xcp[32];
      *(float4*)&xv[4] = *(const float4*)&xcp[36];
      split_frag8(xv, xh1, xl1);
#pragma unroll
      for (int tt = 0; tt < 4; ++tt) {
        bhalf8 wh, wl;
        zba[tt] = (floatx4){0.f, 0.f, 0.f, 0.f};
        split_frag8(&w1m[tt * 16], wh, wl);
        MFMA3(zba[tt], xh0, xl0, wh, wl);
        split_frag8(&w1m[tt * 16 + 8], wh, wl);
        MFMA3(zba[tt], xh1, xl1, wh, wl);
      }
    }
    __syncthreads();

    // ========== P5: A: Z1b finalize -> sZb | B: XA prefetch ==============
    if (isA) {
#pragma unroll
      for (int tt = 0; tt < 4; ++tt) {
        const int n = 64 * w + 16 * tt + fr;
        float gv[16];
        *(float4*)&gv[0]  = *(const float4*)&sG1[n * 20 + 0];
        *(float4*)&gv[4]  = *(const float4*)&sG1[n * 20 + 4];
        *(float4*)&gv[8]  = *(const float4*)&sG1[n * 20 + 8];
        *(float4*)&gv[12] = *(const float4*)&sG1[n * 20 + 12];
#pragma unroll
        for (int j = 0; j < 4; ++j) {
          const int i = 4 * fg + j;
          float at = 0.f;
#pragma unroll
          for (int jp = 0; jp < 16; ++jp)
            at = fmaf(sA1[i * 17 + jp], gv[jp], at);   // upper tri of A1 is 0
          const float z = zba[tt][j] - sCo[cur * 16 + i] * at;
          unsigned short hs, ls; tsplit(z, hs, ls);
          sZbh[i * 264 + n] = hs;
          sZbl[i * 264 + n] = ls;
        }
      }
    } else {
#pragma unroll
      for (int j = 0; j < 4; ++j)
        xar[j] = XA[cb1 + (4 * fg + j) * 1024 + m];
    }
    __syncthreads();

    // ========== P6: A: Attn2 + W1up | B: Z2b + W2up ======================
    if (isA) {
      floatx4 a2 = (floatx4){0.f, 0.f, 0.f, 0.f};
#pragma unroll
      for (int ksl = 0; ksl < 2; ++ksl) {
        const int ks = 2 * w + ksl;
        const bhalf8 ah  = *(const bhalf8*)&sZbh[fr * 264 + 32 * ks + 8 * fg];
        const bhalf8 al  = *(const bhalf8*)&sZbl[fr * 264 + 32 * ks + 8 * fg];
        const bhalf8 bhf = *(const bhalf8*)&sZ1h[fr * 264 + 32 * ks + 8 * fg];
        const bhalf8 blf = *(const bhalf8*)&sZ1l[fr * 264 + 32 * ks + 8 * fg];
        MFMA3(a2, ah, al, bhf, blf);
      }
#pragma unroll
      for (int j = 0; j < 4; ++j) {
        const int i = 4 * fg + j;
        sA2p[w * 272 + i * 17 + fr] = (fr <= i) ? a2[j] : 0.f;
      }
      const float cl = sCo[cur * 16 + 15];
#pragma unroll
      for (int i = 0; i < 16; ++i) {
        const float cg0 = cl * sG1[(64 * w +  0 + fr) * 20 + i];
        const float cg1 = cl * sG1[(64 * w + 16 + fr) * 20 + i];
        const float cg2 = cl * sG1[(64 * w + 32 + fr) * 20 + i];
        const float cg3 = cl * sG1[(64 * w + 48 + fr) * 20 + i];
#pragma unroll
        for (int ks = 0; ks < 2; ++ks)
#pragma unroll
          for (int e = 0; e < 8; ++e) {
            const float xb = sXBt[i * 68 + 32 * ks + 8 * fg + e];
            w1m[ 0 + ks * 8 + e] = fmaf(-cg0, xb, w1m[ 0 + ks * 8 + e]);
            w1m[16 + ks * 8 + e] = fmaf(-cg1, xb, w1m[16 + ks * 8 + e]);
            w1m[32 + ks * 8 + e] = fmaf(-cg2, xb, w1m[32 + ks * 8 + e]);
            w1m[48 + ks * 8 + e] = fmaf(-cg3, xb, w1m[48 + ks * 8 + e]);
          }
      }
    } else {
      zb2 = (floatx4){0.f, 0.f, 0.f, 0.f};
#pragma unroll
      for (int ks = 0; ks < 8; ++ks) {
        const bhalf8 ah = *(const bhalf8*)&sZbh[fr * 264 + 32 * ks + 8 * fg];
        const bhalf8 al = *(const bhalf8*)&sZbl[fr * 264 + 32 * ks + 8 * fg];
        bhalf8 wh, wl; split_frag8(&w2m[ks * 8], wh, wl);
        MFMA3(zb2, ah, al, wh, wl);
      }
      // W2 update (exact fp32 on masters), i-halved; sZ1t fg-XOR blocks
      const float cl = sCo[cur * 16 + 15];
#pragma unroll
      for (int half = 0; half < 2; ++half) {
        float cg[8];
#pragma unroll
        for (int ii = 0; ii < 8; ++ii)
          cg[ii] = cl * recon2(sg2h[(half * 8 + ii) * 72 + m],
                               sg2l[(half * 8 + ii) * 72 + m]);
#pragma unroll
        for (int ks = 0; ks < 8; ++ks)
#pragma unroll
          for (int e = 0; e < 8; ++e) {
            const int k = 32 * ks + 8 * fg + e;
            const float4 z0 = *(const float4*)&sZ1t[k * 20 + (((2 * half + 0) ^ fg) << 2)];
            const float4 z1 = *(const float4*)&sZ1t[k * 20 + (((2 * half + 1) ^ fg) << 2)];
            float acc = w2m[ks * 8 + e];
            acc = fmaf(-cg[0], z0.x, acc); acc = fmaf(-cg[1], z0.y, acc);
            acc = fmaf(-cg[2], z0.z, acc); acc = fmaf(-cg[3], z0.w, acc);
            acc = fmaf(-cg[4], z1.x, acc); acc = fmaf(-cg[5], z1.y, acc);
            acc = fmaf(-cg[6], z1.z, acc); acc = fmaf(-cg[7], z1.w, acc);
            w2m[ks * 8 + e] = acc;
          }
      }
    }
    __syncthreads();

    // ====== P7: B: Z2b apply + store, sW2 rebuild (no trailing barrier:
    //  A's next P1' writes sZ1h/l, sZ1t, sCo[cur^1] — disjoint from P7) ===
    if (!isA) {
      float at[4] = {0.f, 0.f, 0.f, 0.f};
#pragma unroll
      for (int jp = 0; jp < 16; ++jp) {
        const float g2v = recon2(sg2h[jp * 72 + m], sg2l[jp * 72 + m]);
#pragma unroll
        for (int j = 0; j < 4; ++j) {
          const int i = 4 * fg + j;
          const float a2s = sA2p[i * 17 + jp] + sA2p[272 + i * 17 + jp]
                          + sA2p[544 + i * 17 + jp] + sA2p[816 + i * 17 + jp];
          at[j] = fmaf(a2s, g2v, at[j]);
        }
      }
#pragma unroll
      for (int j = 0; j < 4; ++j) {
        const int i = 4 * fg + j;
        Out[cb + i * 1024 + m] = zb2[j] - sCo[cur * 16 + i] * at[j];
      }
#pragma unroll
      for (int ks = 0; ks < 8; ++ks)
#pragma unroll
        for (int e = 0; e < 8; ++e) {
          const int k = 32 * ks + 8 * fg + e;
          unsigned short hs, ls;
          tsplit(w2m[ks * 8 + e], hs, ls);
          const int idx = W2IDX(k, m);
          sW2h[idx] = hs;
          sW2l[idx] = ls;
        }
    }
  }
}

// ---------------------------------------------------------------------------
// Workspace: bXC [0,16.7M) | bXB [16.7M,33.5M) | bZ2b [33.5M,50.3M) | bCo.
// H-split lives in bZ2b region (dead until scan writes); Z2b-split in bXC
// region (dead after scan).  XA lives in d_out until final GEMM overwrites.
// ---------------------------------------------------------------------------
extern "C" void kernel_launch(void* const* d_in, const int* in_sizes, int n_in,
                              void* d_out, int out_size, void* d_ws, size_t ws_size,
                              hipStream_t stream)
{
  const float* H    = (const float*)d_in[0];
  const float* Wq   = (const float*)d_in[1];
  const float* Wk   = (const float*)d_in[2];
  const float* Wv   = (const float*)d_in[3];
  const float* Wo   = (const float*)d_in[4];
  const float* Wil  = (const float*)d_in[5];
  const float* bil  = (const float*)d_in[6];
  const float* W1   = (const float*)d_in[7];
  const float* W2   = (const float*)d_in[8];
  float* out        = (float*)d_out;

  float* ws    = (float*)d_ws;
  float* bXC   = ws;
  float* bXB   = ws + 16777216;
  float* bZ2b  = ws + 33554432;
  float* bCo   = ws + 50331648;
  float* bXA   = out;

  unsigned short* hHi = (unsigned short*)bZ2b;
  unsigned short* hLo = hHi + 16777216;
  unsigned short* zHi = (unsigned short*)bXC;
  unsigned short* zLo = zHi + 16777216;

  const int M = Bsz * Lsz, N = Csz, K = Csz;
  dim3 gm(N / 128, M / 128);
  dim3 bm(256);

  split32<<<16384, 256, 0, stream>>>(H, hHi, hLo);
  gemm_mfma<<<gm, bm, 0, stream>>>(hHi, hLo, Wq, bXC, M, N, K);
  gemm_mfma<<<gm, bm, 0, stream>>>(hHi, hLo, Wk, bXB, M, N, K);
  gemm_mfma<<<gm, bm, 0, stream>>>(hHi, hLo, Wv, bXA, M, N, K);
  ilr_coeff<<<M / 4, 256, 0, stream>>>(H, Wil, bil, bCo);
  ttt_scan<<<Bsz * NHsz, 512, 0, stream>>>(bXA, bXB, bXC, bCo, W1, W2, bZ2b);
  split32<<<16384, 256, 0, stream>>>(bZ2b, zHi, zLo);
  gemm_mfma<<<gm, bm, 0, stream>>>(zHi, zLo, Wo, out, M, N, K);
}

// Round 12
// 9189.757 us; speedup vs baseline: 1.2215x; 1.2215x over previous
//
#include <hip/hip_runtime.h>

#define Bsz  4
#define Lsz  4096
#define Csz  1024
#define NHsz 16
#define CSsz 16
#define HFsz 64
#define HF4sz 256
#define NCsz 256

typedef __attribute__((ext_vector_type(8))) short  bhalf8;
typedef __attribute__((ext_vector_type(4))) float  floatx4;

// ---------------------------------------------------------------------------
// fp32 -> bf16 helpers.  tsplit: trunc-hi + RNE-lo (x ~= h+l, |err|~2^-16|x|).
// ---------------------------------------------------------------------------
__device__ __forceinline__ unsigned short bf_rne(float x) {
  const unsigned u = __float_as_uint(x);
  return (unsigned short)((u + 0x7fffu + ((u >> 16) & 1u)) >> 16);
}
__device__ __forceinline__ void split_rne(float x, unsigned short& h, unsigned short& l) {
  h = bf_rne(x);
  const float hf = __uint_as_float((unsigned)h << 16);
  l = bf_rne(x - hf);
}
__device__ __forceinline__ void tsplit(float x, unsigned short& h, unsigned short& l) {
  const unsigned u = __float_as_uint(x);
  h = (unsigned short)(u >> 16);
  const float r = x - __uint_as_float(u & 0xffff0000u);
  l = bf_rne(r);
}
__device__ __forceinline__ void split_frag8(const float* __restrict__ x,
                                            bhalf8& h, bhalf8& l) {
#pragma unroll
  for (int e = 0; e < 8; ++e) {
    unsigned short hs, ls;
    tsplit(x[e], hs, ls);
    h[e] = (short)hs; l[e] = (short)ls;
  }
}
__device__ __forceinline__ float recon2(unsigned short h, unsigned short l) {
  return __uint_as_float((unsigned)h << 16) + __uint_as_float((unsigned)l << 16);
}

#define MFMA3(acc, ah, al, bh, bl)                                            \
  acc = __builtin_amdgcn_mfma_f32_16x16x32_bf16(ah, bh, acc, 0, 0, 0);        \
  acc = __builtin_amdgcn_mfma_f32_16x16x32_bf16(ah, bl, acc, 0, 0, 0);        \
  acc = __builtin_amdgcn_mfma_f32_16x16x32_bf16(al, bh, acc, 0, 0, 0);

// ---------------------------------------------------------------------------
// bulk fp32 -> split-bf16 (hi[], lo[]) for the big GEMMs (RNE split).
// ---------------------------------------------------------------------------
__global__ __launch_bounds__(256)
void split32(const float* __restrict__ in, unsigned short* __restrict__ hi,
             unsigned short* __restrict__ lo)
{
  const int i = (blockIdx.x * 256 + threadIdx.x) * 4;
  const float4 v = *(const float4*)&in[i];
  ushort4 h, l;
  split_rne(v.x, h.x, l.x);
  split_rne(v.y, h.y, l.y);
  split_rne(v.z, h.z, l.z);
  split_rne(v.w, h.w, l.w);
  *(ushort4*)&hi[i] = h;
  *(ushort4*)&lo[i] = l;
}

// ---------------------------------------------------------------------------
// MFMA GEMM (validated round 9): C = A@B, A pre-split, B fp32 inline-split.
// ---------------------------------------------------------------------------
__global__ __launch_bounds__(256)
void gemm_mfma(const unsigned short* __restrict__ Ahi,
               const unsigned short* __restrict__ Alo,
               const float* __restrict__ Bm,
               float* __restrict__ Cm, int M, int N, int K)
{
  __shared__ unsigned short sAh[128 * 40];
  __shared__ unsigned short sAl[128 * 40];
  __shared__ unsigned short sBh[128 * 40];
  __shared__ unsigned short sBl[128 * 40];

  const int t    = threadIdx.x;
  const int lane = t & 63, w = t >> 6;
  const int wr   = (w >> 1) * 64, wc = (w & 1) * 64;
  const int row0 = blockIdx.y * 128, col0 = blockIdx.x * 128;
  const int fr   = lane & 15, fk = (lane >> 4) * 8;

  floatx4 acc[4][4];
#pragma unroll
  for (int mi = 0; mi < 4; ++mi)
#pragma unroll
    for (int ni = 0; ni < 4; ++ni) acc[mi][ni] = (floatx4){0.f, 0.f, 0.f, 0.f};

  const int arow = t >> 1, akg = (t & 1) * 16;
  const int bc4  = (t & 31) * 4, bk4 = (t >> 5) * 4;

  for (int k0 = 0; k0 < K; k0 += 32) {
    {
      const size_t ga = (size_t)(row0 + arow) * K + k0 + akg;
      const bhalf8 h0 = *(const bhalf8*)&Ahi[ga];
      const bhalf8 h1 = *(const bhalf8*)&Ahi[ga + 8];
      const bhalf8 l0 = *(const bhalf8*)&Alo[ga];
      const bhalf8 l1 = *(const bhalf8*)&Alo[ga + 8];
      *(bhalf8*)&sAh[arow * 40 + akg]     = h0;
      *(bhalf8*)&sAh[arow * 40 + akg + 8] = h1;
      *(bhalf8*)&sAl[arow * 40 + akg]     = l0;
      *(bhalf8*)&sAl[arow * 40 + akg + 8] = l1;
    }
    {
      const float4 r0 = *(const float4*)&Bm[(size_t)(k0 + bk4 + 0) * N + col0 + bc4];
      const float4 r1 = *(const float4*)&Bm[(size_t)(k0 + bk4 + 1) * N + col0 + bc4];
      const float4 r2 = *(const float4*)&Bm[(size_t)(k0 + bk4 + 2) * N + col0 + bc4];
      const float4 r3 = *(const float4*)&Bm[(size_t)(k0 + bk4 + 3) * N + col0 + bc4];
#define STORE_BCOL(v0, v1, v2, v3, c) do {                                   \
      unsigned short h0_, h1_, h2_, h3_, l0_, l1_, l2_, l3_;                 \
      split_rne(v0, h0_, l0_); split_rne(v1, h1_, l1_);                      \
      split_rne(v2, h2_, l2_); split_rne(v3, h3_, l3_);                      \
      const int off_ = (bc4 + (c)) * 40 + bk4;                               \
      *(unsigned*)&sBh[off_]     = (unsigned)h0_ | ((unsigned)h1_ << 16);    \
      *(unsigned*)&sBh[off_ + 2] = (unsigned)h2_ | ((unsigned)h3_ << 16);    \
      *(unsigned*)&sBl[off_]     = (unsigned)l0_ | ((unsigned)l1_ << 16);    \
      *(unsigned*)&sBl[off_ + 2] = (unsigned)l2_ | ((unsigned)l3_ << 16);    \
    } while (0)
      STORE_BCOL(r0.x, r1.x, r2.x, r3.x, 0);
      STORE_BCOL(r0.y, r1.y, r2.y, r3.y, 1);
      STORE_BCOL(r0.z, r1.z, r2.z, r3.z, 2);
      STORE_BCOL(r0.w, r1.w, r2.w, r3.w, 3);
#undef STORE_BCOL
    }
    __syncthreads();

    bhalf8 ah[4], al[4];
#pragma unroll
    for (int mi = 0; mi < 4; ++mi) {
      ah[mi] = *(const bhalf8*)&sAh[(wr + mi * 16 + fr) * 40 + fk];
      al[mi] = *(const bhalf8*)&sAl[(wr + mi * 16 + fr) * 40 + fk];
    }
#pragma unroll
    for (int ni = 0; ni < 4; ++ni) {
      const bhalf8 bh = *(const bhalf8*)&sBh[(wc + ni * 16 + fr) * 40 + fk];
      const bhalf8 bl = *(const bhalf8*)&sBl[(wc + ni * 16 + fr) * 40 + fk];
#pragma unroll
      for (int mi = 0; mi < 4; ++mi) {
        acc[mi][ni] = __builtin_amdgcn_mfma_f32_16x16x32_bf16(ah[mi], bh, acc[mi][ni], 0, 0, 0);
        acc[mi][ni] = __builtin_amdgcn_mfma_f32_16x16x32_bf16(ah[mi], bl, acc[mi][ni], 0, 0, 0);
        acc[mi][ni] = __builtin_amdgcn_mfma_f32_16x16x32_bf16(al[mi], bh, acc[mi][ni], 0, 0, 0);
      }
    }
    __syncthreads();
  }

  const int er = (lane >> 4) * 4;
#pragma unroll
  for (int mi = 0; mi < 4; ++mi)
#pragma unroll
    for (int ni = 0; ni < 4; ++ni) {
      const size_t base = (size_t)(row0 + wr + mi * 16 + er) * N + col0 + wc + ni * 16 + fr;
#pragma unroll
      for (int j = 0; j < 4; ++j)
        Cm[base + (size_t)j * N] = acc[mi][ni][j];
    }
}

// ---------------------------------------------------------------------------
// ilr -> coeff table (unchanged)
// ---------------------------------------------------------------------------
__global__ __launch_bounds__(256)
void ilr_coeff(const float* __restrict__ H, const float* __restrict__ Wil,
               const float* __restrict__ bil, float* __restrict__ coeff)
{
  __shared__ float sRow[4][1024];
  __shared__ float sP[4][16][17];
  const int t = threadIdx.x;
  const size_t r0 = (size_t)blockIdx.x * 4;
  for (int rr = 0; rr < 4; ++rr)
    for (int c = t; c < 1024; c += 256)
      sRow[rr][c] = H[(r0 + rr) * 1024 + c];
  __syncthreads();
  const int hh = t & 15, sl = t >> 4;
  for (int rr = 0; rr < 4; ++rr) {
    float acc = 0.f;
    for (int kk = 0; kk < 64; ++kk)
      acc += sRow[rr][sl * 64 + kk] * Wil[(sl * 64 + kk) * 16 + hh];
    sP[rr][sl][hh] = acc;
  }
  __syncthreads();
  if (t < 64) {
    const int rr = t >> 4, h2 = t & 15;
    float s = 0.f;
    for (int sl2 = 0; sl2 < 16; ++sl2) s += sP[rr][sl2][h2];
    s += bil[h2];
    const float sig = 1.f / (1.f + expf(-s));
    const int r  = (int)(r0 + rr);
    const int b  = r >> 12, l = r & 4095, nc = l >> 4, cs = l & 15;
    coeff[((b * 16 + h2) * NCsz + nc) * CSsz + cs] = sig / ((float)(cs + 1) * 64.0f);
  }
}

// ---------------------------------------------------------------------------
// TTT scan v14 — v12 (round-10 validated best, 7.95ms) + two surgical
// register-pressure cuts (round-11 post-mortem: v13's bundle regressed;
// WRITE 2.12GB in v12 = ~63 dwords/thread/chunk spilled):
//  (1) z1bp no longer held in regs across P1'->P5 (was zba[4] = 16 VGPRs,
//      4 barriers).  P1' pass-b split-stores it into sZbh/sZbl (dead until
//      P5: written P5, read P6, untouched P7/P1'); P5 reads it back and
//      overwrites with final Z1b.  A persistent state = w1m[64] only.
//  (2) B-side W2 update i-halved: cg[8] + 8 Z1 floats transient (was
//      cg[16]+zr[16] = 32 co-live).  Unswizzled v12 sZ1t layout kept.
// Everything else byte-identical to v12 (phases, layouts, schedule).
// ---------------------------------------------------------------------------
__global__ __launch_bounds__(512)
void ttt_scan(const float* __restrict__ XA, const float* __restrict__ XBuf,
              const float* __restrict__ XCbuf, const float* __restrict__ coeff,
              const float* __restrict__ W1g, const float* __restrict__ W2g,
              float* __restrict__ Out)
{
  __shared__ __attribute__((aligned(16))) unsigned short sW2h[256 * 72]; // 36864
  __shared__ __attribute__((aligned(16))) unsigned short sW2l[256 * 72]; // 36864
  __shared__ __attribute__((aligned(16))) unsigned short sZ1h[16 * 264]; // 8448
  __shared__ __attribute__((aligned(16))) unsigned short sZ1l[16 * 264];
  __shared__ __attribute__((aligned(16))) unsigned short sZbh[16 * 264]; // z1bp | Z1b
  __shared__ __attribute__((aligned(16))) unsigned short sZbl[16 * 264];
  __shared__ __attribute__((aligned(16))) float sZ1t[256 * 20];          // 20480
  __shared__ __attribute__((aligned(16))) float sG1 [256 * 20];          // 20480
  __shared__ __attribute__((aligned(16))) unsigned short sg2h[16 * 72];  // 2304
  __shared__ __attribute__((aligned(16))) unsigned short sg2l[16 * 72];
  __shared__ __attribute__((aligned(16))) float sXBt[64 * 20];           // 5120
  __shared__ __attribute__((aligned(16))) float sA1 [16 * 17];           // 1088
  __shared__ __attribute__((aligned(16))) float sA2p[4 * 16 * 17];       // 4352
  __shared__ __attribute__((aligned(16))) float sCo [2 * 16];            // 128

  const int t    = threadIdx.x;
  const int bh   = blockIdx.x;            // 0..63
  const int b    = bh >> 4, h = bh & 15;
  const bool isA = (t < 256);
  const int lane = t & 63;
  const int fr   = lane & 15, fg = lane >> 4;
  const int w    = t >> 6;                // A: 0..3
  const int tb   = t - 256;               // B local
  const int wb   = (t >> 6) & 3;          // B: 0..3
  const int m    = 16 * wb + fr;          // B: W2 col

  float w1m[64];   // A masters (frag layout: [tt*16 + ks*8 + e])
  float w2m[64];   // B masters (frag layout: [ks*8 + e])
  floatx4 zb2;     // B: Z2b D-frag  (P6 -> P7)
  float xar[4];    // B: XA prefetch

  const float* W1h = W1g + h * HFsz * HF4sz;
  const float* W2h = W2g + h * HF4sz * HFsz;
  if (isA) {
#pragma unroll
    for (int tt = 0; tt < 4; ++tt)
#pragma unroll
      for (int ks = 0; ks < 2; ++ks)
#pragma unroll
        for (int e = 0; e < 8; ++e)
          w1m[tt * 16 + ks * 8 + e] = W1h[(32 * ks + 8 * fg + e) * 256 + (64 * w + 16 * tt + fr)];
  } else {
#pragma unroll
    for (int ks = 0; ks < 8; ++ks)
#pragma unroll
      for (int e = 0; e < 8; ++e)
        w2m[ks * 8 + e] = W2h[(32 * ks + 8 * fg + e) * 64 + m];
#pragma unroll
    for (int ks = 0; ks < 8; ++ks)
#pragma unroll
      for (int e = 0; e < 8; ++e) {
        const int k = 32 * ks + 8 * fg + e;
        unsigned short hs, ls;
        tsplit(w2m[ks * 8 + e], hs, ls);
        sW2h[k * 72 + m] = hs;
        sW2l[k * 72 + m] = ls;
      }
    const int cb0 = (b * Lsz) * Csz + h * HFsz;
#pragma unroll
    for (int j = 0; j < 4; ++j)
      xar[j] = XA[cb0 + (4 * fg + j) * 1024 + m];
  }
  __syncthreads();

#pragma unroll 1
  for (int nc = 0; nc < NCsz; ++nc) {
    const int cur = nc & 1;
    const int cb  = (b * Lsz + nc * CSsz) * Csz + h * HFsz;
    const int nc1 = (nc + 1) & (NCsz - 1);
    const int cb1 = (b * Lsz + nc1 * CSsz) * Csz + h * HFsz;
    const float* __restrict__ xbG = XBuf  + cb;
    const float* __restrict__ xcG = XCbuf + cb;

    // ========= P1': A: Z1 MFMA + z1bp MFMA (split-stored) | B: Attn1 =====
    if (isA) {
      if (t < 16) sCo[cur * 16 + t] = coeff[(bh * NCsz + nc) * CSsz + t];
      const float* __restrict__ xbp = xbG + fr * 1024 + 8 * fg;
      const float* __restrict__ xcp = xcG + fr * 1024 + 8 * fg;
      // pass a: Z1 (tt-outer, single acc live)
      {
        float xv[8];
        bhalf8 xh0, xl0, xh1, xl1;
        *(float4*)&xv[0] = *(const float4*)&xbp[0];
        *(float4*)&xv[4] = *(const float4*)&xbp[4];
        split_frag8(xv, xh0, xl0);
        *(float4*)&xv[0] = *(const float4*)&xbp[32];
        *(float4*)&xv[4] = *(const float4*)&xbp[36];
        split_frag8(xv, xh1, xl1);
#pragma unroll
        for (int tt = 0; tt < 4; ++tt) {
          bhalf8 wh, wl;
          floatx4 acc = (floatx4){0.f, 0.f, 0.f, 0.f};
          split_frag8(&w1m[tt * 16], wh, wl);
          MFMA3(acc, xh0, xl0, wh, wl);
          split_frag8(&w1m[tt * 16 + 8], wh, wl);
          MFMA3(acc, xh1, xl1, wh, wl);
          const int n = 64 * w + 16 * tt + fr;
#pragma unroll
          for (int j = 0; j < 4; ++j) {
            const int i = 4 * fg + j;
            unsigned short hs, ls; tsplit(acc[j], hs, ls);
            sZ1h[i * 264 + n] = hs;
            sZ1l[i * 264 + n] = ls;
            sZ1t[n * 20 + i]  = acc[j];
          }
        }
      }
      // pass b: z1bp -> split-stored to sZb (regs freed; read back in P5)
      {
        float xv[8];
        bhalf8 xh0, xl0, xh1, xl1;
        *(float4*)&xv[0] = *(const float4*)&xcp[0];
        *(float4*)&xv[4] = *(const float4*)&xcp[4];
        split_frag8(xv, xh0, xl0);
        *(float4*)&xv[0] = *(const float4*)&xcp[32];
        *(float4*)&xv[4] = *(const float4*)&xcp[36];
        split_frag8(xv, xh1, xl1);
#pragma unroll
        for (int tt = 0; tt < 4; ++tt) {
          bhalf8 wh, wl;
          floatx4 acc = (floatx4){0.f, 0.f, 0.f, 0.f};
          split_frag8(&w1m[tt * 16], wh, wl);
          MFMA3(acc, xh0, xl0, wh, wl);
          split_frag8(&w1m[tt * 16 + 8], wh, wl);
          MFMA3(acc, xh1, xl1, wh, wl);
          const int n = 64 * w + 16 * tt + fr;
#pragma unroll
          for (int j = 0; j < 4; ++j) {
            const int i = 4 * fg + j;
            unsigned short hs, ls; tsplit(acc[j], hs, ls);
            sZbh[i * 264 + n] = hs;
            sZbl[i * 264 + n] = ls;
          }
        }
      }
    } else {
      const int ia = tb >> 4, ja = tb & 15;
      float a0 = 0.f, a1 = 0.f;
      if (ja <= ia) {
#pragma unroll
        for (int k = 0; k < 64; k += 8) {
          const float4 c0 = *(const float4*)&xcG[ia * 1024 + k];
          const float4 b0 = *(const float4*)&xbG[ja * 1024 + k];
          const float4 c1 = *(const float4*)&xcG[ia * 1024 + k + 4];
          const float4 b1 = *(const float4*)&xbG[ja * 1024 + k + 4];
          a0 = fmaf(c0.w, b0.w, fmaf(c0.z, b0.z, fmaf(c0.y, b0.y, fmaf(c0.x, b0.x, a0))));
          a1 = fmaf(c1.w, b1.w, fmaf(c1.z, b1.z, fmaf(c1.y, b1.y, fmaf(c1.x, b1.x, a1))));
        }
      }
      sA1[ia * 17 + ja] = a0 + a1;   // 0 on upper triangle
    }
    __syncthreads();

    // ================= P2': B: Z2 + g2 | A: XBt stage ====================
    if (!isA) {
      floatx4 z2a = (floatx4){0.f, 0.f, 0.f, 0.f};
#pragma unroll
      for (int ks = 0; ks < 8; ++ks) {
        const bhalf8 ah = *(const bhalf8*)&sZ1h[fr * 264 + 32 * ks + 8 * fg];
        const bhalf8 al = *(const bhalf8*)&sZ1l[fr * 264 + 32 * ks + 8 * fg];
        bhalf8 wh, wl; split_frag8(&w2m[ks * 8], wh, wl);
        MFMA3(z2a, ah, al, wh, wl);
      }
#pragma unroll
      for (int j = 0; j < 4; ++j) {
        const int i = 4 * fg + j;
        const float g2v = z2a[j] - xar[j];
        unsigned short hs, ls; tsplit(g2v, hs, ls);
        sg2h[i * 72 + m] = hs;
        sg2l[i * 72 + m] = ls;
      }
    } else {
      const int ir = t >> 4, k4 = (t & 15) * 4;
      const float4 v = *(const float4*)&xbG[ir * 1024 + k4];
      sXBt[(k4 + 0) * 20 + ir] = v.x;
      sXBt[(k4 + 1) * 20 + ir] = v.y;
      sXBt[(k4 + 2) * 20 + ir] = v.z;
      sXBt[(k4 + 3) * 20 + ir] = v.w;
    }
    __syncthreads();

    // ================= P4: B: g1^T = W2 @ g2^T (MFMA) -> sG1 =============
    if (!isA) {
      floatx4 g1a[4];
#pragma unroll
      for (int r = 0; r < 4; ++r) g1a[r] = (floatx4){0.f, 0.f, 0.f, 0.f};
#pragma unroll
      for (int ks2 = 0; ks2 < 2; ++ks2) {
        const bhalf8 gh = *(const bhalf8*)&sg2h[fr * 72 + 32 * ks2 + 8 * fg];
        const bhalf8 gl = *(const bhalf8*)&sg2l[fr * 72 + 32 * ks2 + 8 * fg];
#pragma unroll
        for (int r = 0; r < 4; ++r) {
          const int rt = 4 * wb + r;
          const bhalf8 ah = *(const bhalf8*)&sW2h[(16 * rt + fr) * 72 + 32 * ks2 + 8 * fg];
          const bhalf8 al = *(const bhalf8*)&sW2l[(16 * rt + fr) * 72 + 32 * ks2 + 8 * fg];
          MFMA3(g1a[r], ah, al, gh, gl);
        }
      }
#pragma unroll
      for (int r = 0; r < 4; ++r) {
        const int rt = 4 * wb + r;
#pragma unroll
        for (int j = 0; j < 4; ++j)
          sG1[(16 * rt + 4 * fg + j) * 20 + fr] = g1a[r][j];
      }
    }
    __syncthreads();

    // ========= P5: A: Z1b finalize (z1bp from sZb) -> sZb ================
    if (isA) {
#pragma unroll
      for (int tt = 0; tt < 4; ++tt) {
        const int n = 64 * w + 16 * tt + fr;
        float gv[16];
        *(float4*)&gv[0]  = *(const float4*)&sG1[n * 20 + 0];
        *(float4*)&gv[4]  = *(const float4*)&sG1[n * 20 + 4];
        *(float4*)&gv[8]  = *(const float4*)&sG1[n * 20 + 8];
        *(float4*)&gv[12] = *(const float4*)&sG1[n * 20 + 12];
#pragma unroll
        for (int j = 0; j < 4; ++j) {
          const int i = 4 * fg + j;
          float at = 0.f;
#pragma unroll
          for (int jp = 0; jp < 16; ++jp)
            at = fmaf(sA1[i * 17 + jp], gv[jp], at);   // upper tri of A1 is 0
          const float z1bp = recon2(sZbh[i * 264 + n], sZbl[i * 264 + n]);
          const float z = z1bp - sCo[cur * 16 + i] * at;
          unsigned short hs, ls; tsplit(z, hs, ls);
          sZbh[i * 264 + n] = hs;
          sZbl[i * 264 + n] = ls;
        }
      }
    }
    __syncthreads();

    // ========== P6: A: Attn2 K-part MFMA + W1up | B: Z2b + W2up ==========
    if (isA) {
      floatx4 a2 = (floatx4){0.f, 0.f, 0.f, 0.f};
#pragma unroll
      for (int ksl = 0; ksl < 2; ++ksl) {
        const int ks = 2 * w + ksl;
        const bhalf8 ah  = *(const bhalf8*)&sZbh[fr * 264 + 32 * ks + 8 * fg];
        const bhalf8 al  = *(const bhalf8*)&sZbl[fr * 264 + 32 * ks + 8 * fg];
        const bhalf8 bhf = *(const bhalf8*)&sZ1h[fr * 264 + 32 * ks + 8 * fg];
        const bhalf8 blf = *(const bhalf8*)&sZ1l[fr * 264 + 32 * ks + 8 * fg];
        MFMA3(a2, ah, al, bhf, blf);
      }
#pragma unroll
      for (int j = 0; j < 4; ++j) {
        const int i = 4 * fg + j;
        sA2p[w * 272 + i * 17 + fr] = (fr <= i) ? a2[j] : 0.f;
      }
      // W1 update (exact fp32 on masters)
      const float cl = sCo[cur * 16 + 15];
#pragma unroll
      for (int i = 0; i < 16; ++i) {
        float cg[4];
#pragma unroll
        for (int tt = 0; tt < 4; ++tt)
          cg[tt] = cl * sG1[(64 * w + 16 * tt + fr) * 20 + i];
#pragma unroll
        for (int ks = 0; ks < 2; ++ks)
#pragma unroll
          for (int e = 0; e < 8; ++e) {
            const float xb = sXBt[(32 * ks + 8 * fg + e) * 20 + i];
#pragma unroll
            for (int tt = 0; tt < 4; ++tt)
              w1m[tt * 16 + ks * 8 + e] = fmaf(-cg[tt], xb, w1m[tt * 16 + ks * 8 + e]);
          }
      }
    } else {
      // Z2b (pre-update W2)
      zb2 = (floatx4){0.f, 0.f, 0.f, 0.f};
#pragma unroll
      for (int ks = 0; ks < 8; ++ks) {
        const bhalf8 ah = *(const bhalf8*)&sZbh[fr * 264 + 32 * ks + 8 * fg];
        const bhalf8 al = *(const bhalf8*)&sZbl[fr * 264 + 32 * ks + 8 * fg];
        bhalf8 wh, wl; split_frag8(&w2m[ks * 8], wh, wl);
        MFMA3(zb2, ah, al, wh, wl);
      }
      // W2 update (exact fp32 on masters), i-halved (cg[8] + 8 floats)
      const float cl = sCo[cur * 16 + 15];
#pragma unroll
      for (int half = 0; half < 2; ++half) {
        float cg[8];
#pragma unroll
        for (int ii = 0; ii < 8; ++ii)
          cg[ii] = cl * recon2(sg2h[(half * 8 + ii) * 72 + m],
                               sg2l[(half * 8 + ii) * 72 + m]);
#pragma unroll
        for (int ks = 0; ks < 8; ++ks)
#pragma unroll
          for (int e = 0; e < 8; ++e) {
            const int k = 32 * ks + 8 * fg + e;
            const float4 z0 = *(const float4*)&sZ1t[k * 20 + half * 8 + 0];
            const float4 z1 = *(const float4*)&sZ1t[k * 20 + half * 8 + 4];
            float acc = w2m[ks * 8 + e];
            acc = fmaf(-cg[0], z0.x, acc); acc = fmaf(-cg[1], z0.y, acc);
            acc = fmaf(-cg[2], z0.z, acc); acc = fmaf(-cg[3], z0.w, acc);
            acc = fmaf(-cg[4], z1.x, acc); acc = fmaf(-cg[5], z1.y, acc);
            acc = fmaf(-cg[6], z1.z, acc); acc = fmaf(-cg[7], z1.w, acc);
            w2m[ks * 8 + e] = acc;
          }
      }
    }
    __syncthreads();

    // ====== P7: B: Z2b apply + store, sW2 rebuild, XA prefetch ===========
    //  (no trailing barrier: A's next P1' writes sZ1h/l, sZ1t, sZbh/l,
    //   sCo[cur^1] — none of which P7 reads)
    if (!isA) {
      float at[4] = {0.f, 0.f, 0.f, 0.f};
#pragma unroll
      for (int jp = 0; jp < 16; ++jp) {
        const float g2v = recon2(sg2h[jp * 72 + m], sg2l[jp * 72 + m]);
#pragma unroll
        for (int j = 0; j < 4; ++j) {
          const int i = 4 * fg + j;
          const float a2s = sA2p[i * 17 + jp] + sA2p[272 + i * 17 + jp]
                          + sA2p[544 + i * 17 + jp] + sA2p[816 + i * 17 + jp];
          at[j] = fmaf(a2s, g2v, at[j]);
        }
      }
#pragma unroll
      for (int j = 0; j < 4; ++j) {
        const int i = 4 * fg + j;
        Out[cb + i * 1024 + m] = zb2[j] - sCo[cur * 16 + i] * at[j];
      }
      // rebuild split W2 for next chunk's g1
#pragma unroll
      for (int ks = 0; ks < 8; ++ks)
#pragma unroll
        for (int e = 0; e < 8; ++e) {
          const int k = 32 * ks + 8 * fg + e;
          unsigned short hs, ls;
          tsplit(w2m[ks * 8 + e], hs, ls);
          sW2h[k * 72 + m] = hs;
          sW2l[k * 72 + m] = ls;
        }
      // XA prefetch for next chunk
#pragma unroll
      for (int j = 0; j < 4; ++j)
        xar[j] = XA[cb1 + (4 * fg + j) * 1024 + m];
    }
  }
}

// ---------------------------------------------------------------------------
// Workspace: bXC [0,16.7M) | bXB [16.7M,33.5M) | bZ2b [33.5M,50.3M) | bCo.
// H-split lives in bZ2b region (dead until scan writes); Z2b-split in bXC
// region (dead after scan).  XA lives in d_out until final GEMM overwrites.
// ---------------------------------------------------------------------------
extern "C" void kernel_launch(void* const* d_in, const int* in_sizes, int n_in,
                              void* d_out, int out_size, void* d_ws, size_t ws_size,
                              hipStream_t stream)
{
  const float* H    = (const float*)d_in[0];
  const float* Wq   = (const float*)d_in[1];
  const float* Wk   = (const float*)d_in[2];
  const float* Wv   = (const float*)d_in[3];
  const float* Wo   = (const float*)d_in[4];
  const float* Wil  = (const float*)d_in[5];
  const float* bil  = (const float*)d_in[6];
  const float* W1   = (const float*)d_in[7];
  const float* W2   = (const float*)d_in[8];
  float* out        = (float*)d_out;

  float* ws    = (float*)d_ws;
  float* bXC   = ws;
  float* bXB   = ws + 16777216;
  float* bZ2b  = ws + 33554432;
  float* bCo   = ws + 50331648;
  float* bXA   = out;

  unsigned short* hHi = (unsigned short*)bZ2b;
  unsigned short* hLo = hHi + 16777216;
  unsigned short* zHi = (unsigned short*)bXC;
  unsigned short* zLo = zHi + 16777216;

  const int M = Bsz * Lsz, N = Csz, K = Csz;
  dim3 gm(N / 128, M / 128);
  dim3 bm(256);

  split32<<<16384, 256, 0, stream>>>(H, hHi, hLo);
  gemm_mfma<<<gm, bm, 0, stream>>>(hHi, hLo, Wq, bXC, M, N, K);
  gemm_mfma<<<gm, bm, 0, stream>>>(hHi, hLo, Wk, bXB, M, N, K);
  gemm_mfma<<<gm, bm, 0, stream>>>(hHi, hLo, Wv, bXA, M, N, K);
  ilr_coeff<<<M / 4, 256, 0, stream>>>(H, Wil, bil, bCo);
  ttt_scan<<<Bsz * NHsz, 512, 0, stream>>>(bXA, bXB, bXC, bCo, W1, W2, bZ2b);
  split32<<<16384, 256, 0, stream>>>(bZ2b, zHi, zLo);
  gemm_mfma<<<gm, bm, 0, stream>>>(zHi, zLo, Wo, out, M, N, K);
}

// Round 13
// 8549.187 us; speedup vs baseline: 1.3130x; 1.0749x over previous
//
#include <hip/hip_runtime.h>

#define Bsz  4
#define Lsz  4096
#define Csz  1024
#define NHsz 16
#define CSsz 16
#define HFsz 64
#define HF4sz 256
#define NCsz 256

typedef __attribute__((ext_vector_type(8))) short  bhalf8;
typedef __attribute__((ext_vector_type(4))) float  floatx4;

// ---------------------------------------------------------------------------
// fp32 -> bf16 helpers.  tsplit: trunc-hi + RNE-lo (x ~= h+l, |err|~2^-16|x|).
// ---------------------------------------------------------------------------
__device__ __forceinline__ unsigned short bf_rne(float x) {
  const unsigned u = __float_as_uint(x);
  return (unsigned short)((u + 0x7fffu + ((u >> 16) & 1u)) >> 16);
}
__device__ __forceinline__ void split_rne(float x, unsigned short& h, unsigned short& l) {
  h = bf_rne(x);
  const float hf = __uint_as_float((unsigned)h << 16);
  l = bf_rne(x - hf);
}
__device__ __forceinline__ void tsplit(float x, unsigned short& h, unsigned short& l) {
  const unsigned u = __float_as_uint(x);
  h = (unsigned short)(u >> 16);
  const float r = x - __uint_as_float(u & 0xffff0000u);
  l = bf_rne(r);
}
__device__ __forceinline__ void split_frag8(const float* __restrict__ x,
                                            bhalf8& h, bhalf8& l) {
#pragma unroll
  for (int e = 0; e < 8; ++e) {
    unsigned short hs, ls;
    tsplit(x[e], hs, ls);
    h[e] = (short)hs; l[e] = (short)ls;
  }
}
__device__ __forceinline__ float recon2(unsigned short h, unsigned short l) {
  return __uint_as_float((unsigned)h << 16) + __uint_as_float((unsigned)l << 16);
}

#define MFMA3(acc, ah, al, bh, bl)                                            \
  acc = __builtin_amdgcn_mfma_f32_16x16x32_bf16(ah, bh, acc, 0, 0, 0);        \
  acc = __builtin_amdgcn_mfma_f32_16x16x32_bf16(ah, bl, acc, 0, 0, 0);        \
  acc = __builtin_amdgcn_mfma_f32_16x16x32_bf16(al, bh, acc, 0, 0, 0);

// ---------------------------------------------------------------------------
// bulk fp32 -> split-bf16 (hi[], lo[]) for the big GEMMs (RNE split).
// ---------------------------------------------------------------------------
__global__ __launch_bounds__(256)
void split32(const float* __restrict__ in, unsigned short* __restrict__ hi,
             unsigned short* __restrict__ lo)
{
  const int i = (blockIdx.x * 256 + threadIdx.x) * 4;
  const float4 v = *(const float4*)&in[i];
  ushort4 h, l;
  split_rne(v.x, h.x, l.x);
  split_rne(v.y, h.y, l.y);
  split_rne(v.z, h.z, l.z);
  split_rne(v.w, h.w, l.w);
  *(ushort4*)&hi[i] = h;
  *(ushort4*)&lo[i] = l;
}

// ---------------------------------------------------------------------------
// MFMA GEMM (validated round 9): C = A@B, A pre-split, B fp32 inline-split.
// ---------------------------------------------------------------------------
__global__ __launch_bounds__(256)
void gemm_mfma(const unsigned short* __restrict__ Ahi,
               const unsigned short* __restrict__ Alo,
               const float* __restrict__ Bm,
               float* __restrict__ Cm, int M, int N, int K)
{
  __shared__ unsigned short sAh[128 * 40];
  __shared__ unsigned short sAl[128 * 40];
  __shared__ unsigned short sBh[128 * 40];
  __shared__ unsigned short sBl[128 * 40];

  const int t    = threadIdx.x;
  const int lane = t & 63, w = t >> 6;
  const int wr   = (w >> 1) * 64, wc = (w & 1) * 64;
  const int row0 = blockIdx.y * 128, col0 = blockIdx.x * 128;
  const int fr   = lane & 15, fk = (lane >> 4) * 8;

  floatx4 acc[4][4];
#pragma unroll
  for (int mi = 0; mi < 4; ++mi)
#pragma unroll
    for (int ni = 0; ni < 4; ++ni) acc[mi][ni] = (floatx4){0.f, 0.f, 0.f, 0.f};

  const int arow = t >> 1, akg = (t & 1) * 16;
  const int bc4  = (t & 31) * 4, bk4 = (t >> 5) * 4;

  for (int k0 = 0; k0 < K; k0 += 32) {
    {
      const size_t ga = (size_t)(row0 + arow) * K + k0 + akg;
      const bhalf8 h0 = *(const bhalf8*)&Ahi[ga];
      const bhalf8 h1 = *(const bhalf8*)&Ahi[ga + 8];
      const bhalf8 l0 = *(const bhalf8*)&Alo[ga];
      const bhalf8 l1 = *(const bhalf8*)&Alo[ga + 8];
      *(bhalf8*)&sAh[arow * 40 + akg]     = h0;
      *(bhalf8*)&sAh[arow * 40 + akg + 8] = h1;
      *(bhalf8*)&sAl[arow * 40 + akg]     = l0;
      *(bhalf8*)&sAl[arow * 40 + akg + 8] = l1;
    }
    {
      const float4 r0 = *(const float4*)&Bm[(size_t)(k0 + bk4 + 0) * N + col0 + bc4];
      const float4 r1 = *(const float4*)&Bm[(size_t)(k0 + bk4 + 1) * N + col0 + bc4];
      const float4 r2 = *(const float4*)&Bm[(size_t)(k0 + bk4 + 2) * N + col0 + bc4];
      const float4 r3 = *(const float4*)&Bm[(size_t)(k0 + bk4 + 3) * N + col0 + bc4];
#define STORE_BCOL(v0, v1, v2, v3, c) do {                                   \
      unsigned short h0_, h1_, h2_, h3_, l0_, l1_, l2_, l3_;                 \
      split_rne(v0, h0_, l0_); split_rne(v1, h1_, l1_);                      \
      split_rne(v2, h2_, l2_); split_rne(v3, h3_, l3_);                      \
      const int off_ = (bc4 + (c)) * 40 + bk4;                               \
      *(unsigned*)&sBh[off_]     = (unsigned)h0_ | ((unsigned)h1_ << 16);    \
      *(unsigned*)&sBh[off_ + 2] = (unsigned)h2_ | ((unsigned)h3_ << 16);    \
      *(unsigned*)&sBl[off_]     = (unsigned)l0_ | ((unsigned)l1_ << 16);    \
      *(unsigned*)&sBl[off_ + 2] = (unsigned)l2_ | ((unsigned)l3_ << 16);    \
    } while (0)
      STORE_BCOL(r0.x, r1.x, r2.x, r3.x, 0);
      STORE_BCOL(r0.y, r1.y, r2.y, r3.y, 1);
      STORE_BCOL(r0.z, r1.z, r2.z, r3.z, 2);
      STORE_BCOL(r0.w, r1.w, r2.w, r3.w, 3);
#undef STORE_BCOL
    }
    __syncthreads();

    bhalf8 ah[4], al[4];
#pragma unroll
    for (int mi = 0; mi < 4; ++mi) {
      ah[mi] = *(const bhalf8*)&sAh[(wr + mi * 16 + fr) * 40 + fk];
      al[mi] = *(const bhalf8*)&sAl[(wr + mi * 16 + fr) * 40 + fk];
    }
#pragma unroll
    for (int ni = 0; ni < 4; ++ni) {
      const bhalf8 bh = *(const bhalf8*)&sBh[(wc + ni * 16 + fr) * 40 + fk];
      const bhalf8 bl = *(const bhalf8*)&sBl[(wc + ni * 16 + fr) * 40 + fk];
#pragma unroll
      for (int mi = 0; mi < 4; ++mi) {
        acc[mi][ni] = __builtin_amdgcn_mfma_f32_16x16x32_bf16(ah[mi], bh, acc[mi][ni], 0, 0, 0);
        acc[mi][ni] = __builtin_amdgcn_mfma_f32_16x16x32_bf16(ah[mi], bl, acc[mi][ni], 0, 0, 0);
        acc[mi][ni] = __builtin_amdgcn_mfma_f32_16x16x32_bf16(al[mi], bh, acc[mi][ni], 0, 0, 0);
      }
    }
    __syncthreads();
  }

  const int er = (lane >> 4) * 4;
#pragma unroll
  for (int mi = 0; mi < 4; ++mi)
#pragma unroll
    for (int ni = 0; ni < 4; ++ni) {
      const size_t base = (size_t)(row0 + wr + mi * 16 + er) * N + col0 + wc + ni * 16 + fr;
#pragma unroll
      for (int j = 0; j < 4; ++j)
        Cm[base + (size_t)j * N] = acc[mi][ni][j];
    }
}

// ---------------------------------------------------------------------------
// ilr -> coeff table (unchanged)
// ---------------------------------------------------------------------------
__global__ __launch_bounds__(256)
void ilr_coeff(const float* __restrict__ H, const float* __restrict__ Wil,
               const float* __restrict__ bil, float* __restrict__ coeff)
{
  __shared__ float sRow[4][1024];
  __shared__ float sP[4][16][17];
  const int t = threadIdx.x;
  const size_t r0 = (size_t)blockIdx.x * 4;
  for (int rr = 0; rr < 4; ++rr)
    for (int c = t; c < 1024; c += 256)
      sRow[rr][c] = H[(r0 + rr) * 1024 + c];
  __syncthreads();
  const int hh = t & 15, sl = t >> 4;
  for (int rr = 0; rr < 4; ++rr) {
    float acc = 0.f;
    for (int kk = 0; kk < 64; ++kk)
      acc += sRow[rr][sl * 64 + kk] * Wil[(sl * 64 + kk) * 16 + hh];
    sP[rr][sl][hh] = acc;
  }
  __syncthreads();
  if (t < 64) {
    const int rr = t >> 4, h2 = t & 15;
    float s = 0.f;
    for (int sl2 = 0; sl2 < 16; ++sl2) s += sP[rr][sl2][h2];
    s += bil[h2];
    const float sig = 1.f / (1.f + expf(-s));
    const int r  = (int)(r0 + rr);
    const int b  = r >> 12, l = r & 4095, nc = l >> 4, cs = l & 15;
    coeff[((b * 16 + h2) * NCsz + nc) * CSsz + cs] = sig / ((float)(cs + 1) * 64.0f);
  }
}

// ---------------------------------------------------------------------------
// TTT scan v15 — round-10 v12 (validated 7.95ms) + union-overlay fix.
//
// Round-12 post-mortem: v14 removed 16-32 branch-LOCAL regs but WRITE
// stayed 2.4GB -> spills don't come from branch-local state.  Real source:
// w1m[64] (A-only) and w2m[64] (B-only) are SEPARATE arrays whose live
// ranges span the whole loop -> allocator unions them = 128 persistent
// VGPRs before any temp.  Same bug as round 2; same fix as round 3's
// wreg overlay:
//  (1) ONE shared array wm[64]: A reads it as W1 fragments, B as W2
//      fragments.  Union persistent 148 -> ~88.
//  (2) W2 update i-halved (cg[8], from v14 — local transient cut).
// Everything else byte-identical to round-10 v12.
// ---------------------------------------------------------------------------
__global__ __launch_bounds__(512)
void ttt_scan(const float* __restrict__ XA, const float* __restrict__ XBuf,
              const float* __restrict__ XCbuf, const float* __restrict__ coeff,
              const float* __restrict__ W1g, const float* __restrict__ W2g,
              float* __restrict__ Out)
{
  __shared__ __attribute__((aligned(16))) unsigned short sW2h[256 * 72]; // 36864
  __shared__ __attribute__((aligned(16))) unsigned short sW2l[256 * 72]; // 36864
  __shared__ __attribute__((aligned(16))) unsigned short sZ1h[16 * 264]; // 8448
  __shared__ __attribute__((aligned(16))) unsigned short sZ1l[16 * 264];
  __shared__ __attribute__((aligned(16))) unsigned short sZbh[16 * 264];
  __shared__ __attribute__((aligned(16))) unsigned short sZbl[16 * 264];
  __shared__ __attribute__((aligned(16))) float sZ1t[256 * 20];          // 20480
  __shared__ __attribute__((aligned(16))) float sG1 [256 * 20];          // 20480
  __shared__ __attribute__((aligned(16))) unsigned short sg2h[16 * 72];  // 2304
  __shared__ __attribute__((aligned(16))) unsigned short sg2l[16 * 72];
  __shared__ __attribute__((aligned(16))) float sXBt[64 * 20];           // 5120
  __shared__ __attribute__((aligned(16))) float sA1 [16 * 17];           // 1088
  __shared__ __attribute__((aligned(16))) float sA2p[4 * 16 * 17];       // 4352
  __shared__ __attribute__((aligned(16))) float sCo [2 * 16];            // 128

  const int t    = threadIdx.x;
  const int bh   = blockIdx.x;            // 0..63
  const int b    = bh >> 4, h = bh & 15;
  const bool isA = (t < 256);
  const int lane = t & 63;
  const int fr   = lane & 15, fg = lane >> 4;
  const int w    = t >> 6;                // A: 0..3
  const int tb   = t - 256;               // B local
  const int wb   = (t >> 6) & 3;          // B: 0..3
  const int m    = 16 * wb + fr;          // B: W2 col

  // SHARED overlay: A-threads: wm = W1 frags [tt*16+ks*8+e];
  //                 B-threads: wm = W2 frags [ks*8+e].
  float wm[64];
  floatx4 zba[4];  // A: z1bp D-frags (P1' -> P5)
  floatx4 zb2;     // B: Z2b D-frag  (P6 -> P7)
  float xar[4];    // B: XA prefetch

  const float* W1h = W1g + h * HFsz * HF4sz;
  const float* W2h = W2g + h * HF4sz * HFsz;
  if (isA) {
#pragma unroll
    for (int tt = 0; tt < 4; ++tt)
#pragma unroll
      for (int ks = 0; ks < 2; ++ks)
#pragma unroll
        for (int e = 0; e < 8; ++e)
          wm[tt * 16 + ks * 8 + e] = W1h[(32 * ks + 8 * fg + e) * 256 + (64 * w + 16 * tt + fr)];
  } else {
#pragma unroll
    for (int ks = 0; ks < 8; ++ks)
#pragma unroll
      for (int e = 0; e < 8; ++e)
        wm[ks * 8 + e] = W2h[(32 * ks + 8 * fg + e) * 64 + m];
#pragma unroll
    for (int ks = 0; ks < 8; ++ks)
#pragma unroll
      for (int e = 0; e < 8; ++e) {
        const int k = 32 * ks + 8 * fg + e;
        unsigned short hs, ls;
        tsplit(wm[ks * 8 + e], hs, ls);
        sW2h[k * 72 + m] = hs;
        sW2l[k * 72 + m] = ls;
      }
    const int cb0 = (b * Lsz) * Csz + h * HFsz;
#pragma unroll
    for (int j = 0; j < 4; ++j)
      xar[j] = XA[cb0 + (4 * fg + j) * 1024 + m];
  }
  __syncthreads();

#pragma unroll 1
  for (int nc = 0; nc < NCsz; ++nc) {
    const int cur = nc & 1;
    const int cb  = (b * Lsz + nc * CSsz) * Csz + h * HFsz;
    const int nc1 = (nc + 1) & (NCsz - 1);
    const int cb1 = (b * Lsz + nc1 * CSsz) * Csz + h * HFsz;
    const float* __restrict__ xbG = XBuf  + cb;
    const float* __restrict__ xcG = XCbuf + cb;

    // ================= P1': A: Z1 + z1bp MFMA | B: Attn1 =================
    if (isA) {
      if (t < 16) sCo[cur * 16 + t] = coeff[(bh * NCsz + nc) * CSsz + t];
      const float* __restrict__ xbp = xbG + fr * 1024 + 8 * fg;
      const float* __restrict__ xcp = xcG + fr * 1024 + 8 * fg;
      // pass a: Z1
      {
        float xv[8];
        bhalf8 xh0, xl0, xh1, xl1;
        *(float4*)&xv[0] = *(const float4*)&xbp[0];
        *(float4*)&xv[4] = *(const float4*)&xbp[4];
        split_frag8(xv, xh0, xl0);
        *(float4*)&xv[0] = *(const float4*)&xbp[32];
        *(float4*)&xv[4] = *(const float4*)&xbp[36];
        split_frag8(xv, xh1, xl1);
#pragma unroll
        for (int tt = 0; tt < 4; ++tt) {
          bhalf8 wh, wl;
          floatx4 acc = (floatx4){0.f, 0.f, 0.f, 0.f};
          split_frag8(&wm[tt * 16], wh, wl);
          MFMA3(acc, xh0, xl0, wh, wl);
          split_frag8(&wm[tt * 16 + 8], wh, wl);
          MFMA3(acc, xh1, xl1, wh, wl);
          const int n = 64 * w + 16 * tt + fr;
#pragma unroll
          for (int j = 0; j < 4; ++j) {
            const int i = 4 * fg + j;
            unsigned short hs, ls; tsplit(acc[j], hs, ls);
            sZ1h[i * 264 + n] = hs;
            sZ1l[i * 264 + n] = ls;
            sZ1t[n * 20 + i]  = acc[j];
          }
        }
      }
      // pass b: z1bp (kept in regs to P5)
      {
        float xv[8];
        bhalf8 xh0, xl0, xh1, xl1;
        *(float4*)&xv[0] = *(const float4*)&xcp[0];
        *(float4*)&xv[4] = *(const float4*)&xcp[4];
        split_frag8(xv, xh0, xl0);
        *(float4*)&xv[0] = *(const float4*)&xcp[32];
        *(float4*)&xv[4] = *(const float4*)&xcp[36];
        split_frag8(xv, xh1, xl1);
#pragma unroll
        for (int tt = 0; tt < 4; ++tt) {
          bhalf8 wh, wl;
          zba[tt] = (floatx4){0.f, 0.f, 0.f, 0.f};
          split_frag8(&wm[tt * 16], wh, wl);
          MFMA3(zba[tt], xh0, xl0, wh, wl);
          split_frag8(&wm[tt * 16 + 8], wh, wl);
          MFMA3(zba[tt], xh1, xl1, wh, wl);
        }
      }
    } else {
      const int ia = tb >> 4, ja = tb & 15;
      float a0 = 0.f, a1 = 0.f;
      if (ja <= ia) {
#pragma unroll
        for (int k = 0; k < 64; k += 8) {
          const float4 c0 = *(const float4*)&xcG[ia * 1024 + k];
          const float4 b0 = *(const float4*)&xbG[ja * 1024 + k];
          const float4 c1 = *(const float4*)&xcG[ia * 1024 + k + 4];
          const float4 b1 = *(const float4*)&xbG[ja * 1024 + k + 4];
          a0 = fmaf(c0.w, b0.w, fmaf(c0.z, b0.z, fmaf(c0.y, b0.y, fmaf(c0.x, b0.x, a0))));
          a1 = fmaf(c1.w, b1.w, fmaf(c1.z, b1.z, fmaf(c1.y, b1.y, fmaf(c1.x, b1.x, a1))));
        }
      }
      sA1[ia * 17 + ja] = a0 + a1;   // 0 on upper triangle
    }
    __syncthreads();

    // ================= P2': B: Z2 + g2 | A: XBt stage ====================
    if (!isA) {
      floatx4 z2a = (floatx4){0.f, 0.f, 0.f, 0.f};
#pragma unroll
      for (int ks = 0; ks < 8; ++ks) {
        const bhalf8 ah = *(const bhalf8*)&sZ1h[fr * 264 + 32 * ks + 8 * fg];
        const bhalf8 al = *(const bhalf8*)&sZ1l[fr * 264 + 32 * ks + 8 * fg];
        bhalf8 wh, wl; split_frag8(&wm[ks * 8], wh, wl);
        MFMA3(z2a, ah, al, wh, wl);
      }
#pragma unroll
      for (int j = 0; j < 4; ++j) {
        const int i = 4 * fg + j;
        const float g2v = z2a[j] - xar[j];
        unsigned short hs, ls; tsplit(g2v, hs, ls);
        sg2h[i * 72 + m] = hs;
        sg2l[i * 72 + m] = ls;
      }
    } else {
      const int ir = t >> 4, k4 = (t & 15) * 4;
      const float4 v = *(const float4*)&xbG[ir * 1024 + k4];
      sXBt[(k4 + 0) * 20 + ir] = v.x;
      sXBt[(k4 + 1) * 20 + ir] = v.y;
      sXBt[(k4 + 2) * 20 + ir] = v.z;
      sXBt[(k4 + 3) * 20 + ir] = v.w;
    }
    __syncthreads();

    // ================= P4: B: g1^T = W2 @ g2^T (MFMA) -> sG1 =============
    if (!isA) {
      floatx4 g1a[4];
#pragma unroll
      for (int r = 0; r < 4; ++r) g1a[r] = (floatx4){0.f, 0.f, 0.f, 0.f};
#pragma unroll
      for (int ks2 = 0; ks2 < 2; ++ks2) {
        const bhalf8 gh = *(const bhalf8*)&sg2h[fr * 72 + 32 * ks2 + 8 * fg];
        const bhalf8 gl = *(const bhalf8*)&sg2l[fr * 72 + 32 * ks2 + 8 * fg];
#pragma unroll
        for (int r = 0; r < 4; ++r) {
          const int rt = 4 * wb + r;
          const bhalf8 ah = *(const bhalf8*)&sW2h[(16 * rt + fr) * 72 + 32 * ks2 + 8 * fg];
          const bhalf8 al = *(const bhalf8*)&sW2l[(16 * rt + fr) * 72 + 32 * ks2 + 8 * fg];
          MFMA3(g1a[r], ah, al, gh, gl);
        }
      }
#pragma unroll
      for (int r = 0; r < 4; ++r) {
        const int rt = 4 * wb + r;
#pragma unroll
        for (int j = 0; j < 4; ++j)
          sG1[(16 * rt + 4 * fg + j) * 20 + fr] = g1a[r][j];
      }
    }
    __syncthreads();

    // ========== P5: A: Z1b finalize -> sZb | B: (idle) ===================
    if (isA) {
#pragma unroll
      for (int tt = 0; tt < 4; ++tt) {
        const int n = 64 * w + 16 * tt + fr;
        float gv[16];
        *(float4*)&gv[0]  = *(const float4*)&sG1[n * 20 + 0];
        *(float4*)&gv[4]  = *(const float4*)&sG1[n * 20 + 4];
        *(float4*)&gv[8]  = *(const float4*)&sG1[n * 20 + 8];
        *(float4*)&gv[12] = *(const float4*)&sG1[n * 20 + 12];
#pragma unroll
        for (int j = 0; j < 4; ++j) {
          const int i = 4 * fg + j;
          float at = 0.f;
#pragma unroll
          for (int jp = 0; jp < 16; ++jp)
            at = fmaf(sA1[i * 17 + jp], gv[jp], at);   // upper tri of A1 is 0
          const float z = zba[tt][j] - sCo[cur * 16 + i] * at;
          unsigned short hs, ls; tsplit(z, hs, ls);
          sZbh[i * 264 + n] = hs;
          sZbl[i * 264 + n] = ls;
        }
      }
    }
    __syncthreads();

    // ========== P6: A: Attn2 K-part MFMA + W1up | B: Z2b + W2up ==========
    if (isA) {
      floatx4 a2 = (floatx4){0.f, 0.f, 0.f, 0.f};
#pragma unroll
      for (int ksl = 0; ksl < 2; ++ksl) {
        const int ks = 2 * w + ksl;
        const bhalf8 ah  = *(const bhalf8*)&sZbh[fr * 264 + 32 * ks + 8 * fg];
        const bhalf8 al  = *(const bhalf8*)&sZbl[fr * 264 + 32 * ks + 8 * fg];
        const bhalf8 bhf = *(const bhalf8*)&sZ1h[fr * 264 + 32 * ks + 8 * fg];
        const bhalf8 blf = *(const bhalf8*)&sZ1l[fr * 264 + 32 * ks + 8 * fg];
        MFMA3(a2, ah, al, bhf, blf);
      }
#pragma unroll
      for (int j = 0; j < 4; ++j) {
        const int i = 4 * fg + j;
        sA2p[w * 272 + i * 17 + fr] = (fr <= i) ? a2[j] : 0.f;
      }
      // W1 update (exact fp32 on masters)
      const float cl = sCo[cur * 16 + 15];
#pragma unroll
      for (int i = 0; i < 16; ++i) {
        float cg[4];
#pragma unroll
        for (int tt = 0; tt < 4; ++tt)
          cg[tt] = cl * sG1[(64 * w + 16 * tt + fr) * 20 + i];
#pragma unroll
        for (int ks = 0; ks < 2; ++ks)
#pragma unroll
          for (int e = 0; e < 8; ++e) {
            const float xb = sXBt[(32 * ks + 8 * fg + e) * 20 + i];
#pragma unroll
            for (int tt = 0; tt < 4; ++tt)
              wm[tt * 16 + ks * 8 + e] = fmaf(-cg[tt], xb, wm[tt * 16 + ks * 8 + e]);
          }
      }
    } else {
      // Z2b (pre-update W2)
      zb2 = (floatx4){0.f, 0.f, 0.f, 0.f};
#pragma unroll
      for (int ks = 0; ks < 8; ++ks) {
        const bhalf8 ah = *(const bhalf8*)&sZbh[fr * 264 + 32 * ks + 8 * fg];
        const bhalf8 al = *(const bhalf8*)&sZbl[fr * 264 + 32 * ks + 8 * fg];
        bhalf8 wh, wl; split_frag8(&wm[ks * 8], wh, wl);
        MFMA3(zb2, ah, al, wh, wl);
      }
      // W2 update (exact fp32 on masters), i-halved (cg[8] + 8 Z1 floats)
      const float cl = sCo[cur * 16 + 15];
#pragma unroll
      for (int half = 0; half < 2; ++half) {
        float cg[8];
#pragma unroll
        for (int ii = 0; ii < 8; ++ii)
          cg[ii] = cl * recon2(sg2h[(half * 8 + ii) * 72 + m],
                               sg2l[(half * 8 + ii) * 72 + m]);
#pragma unroll
        for (int ks = 0; ks < 8; ++ks)
#pragma unroll
          for (int e = 0; e < 8; ++e) {
            const int k = 32 * ks + 8 * fg + e;
            const float4 z0 = *(const float4*)&sZ1t[k * 20 + half * 8 + 0];
            const float4 z1 = *(const float4*)&sZ1t[k * 20 + half * 8 + 4];
            float acc = wm[ks * 8 + e];
            acc = fmaf(-cg[0], z0.x, acc); acc = fmaf(-cg[1], z0.y, acc);
            acc = fmaf(-cg[2], z0.z, acc); acc = fmaf(-cg[3], z0.w, acc);
            acc = fmaf(-cg[4], z1.x, acc); acc = fmaf(-cg[5], z1.y, acc);
            acc = fmaf(-cg[6], z1.z, acc); acc = fmaf(-cg[7], z1.w, acc);
            wm[ks * 8 + e] = acc;
          }
      }
    }
    __syncthreads();

    // ====== P7: B: Z2b apply + store, sW2 rebuild, XA prefetch ===========
    //  (no trailing barrier: A's next P1' writes sZ1h/l, sZ1t, sCo[cur^1]
    //   — disjoint from P7's reads/writes)
    if (!isA) {
      float at[4] = {0.f, 0.f, 0.f, 0.f};
#pragma unroll
      for (int jp = 0; jp < 16; ++jp) {
        const float g2v = recon2(sg2h[jp * 72 + m], sg2l[jp * 72 + m]);
#pragma unroll
        for (int j = 0; j < 4; ++j) {
          const int i = 4 * fg + j;
          const float a2s = sA2p[i * 17 + jp] + sA2p[272 + i * 17 + jp]
                          + sA2p[544 + i * 17 + jp] + sA2p[816 + i * 17 + jp];
          at[j] = fmaf(a2s, g2v, at[j]);
        }
      }
#pragma unroll
      for (int j = 0; j < 4; ++j) {
        const int i = 4 * fg + j;
        Out[cb + i * 1024 + m] = zb2[j] - sCo[cur * 16 + i] * at[j];
      }
      // rebuild split W2 for next chunk's g1
#pragma unroll
      for (int ks = 0; ks < 8; ++ks)
#pragma unroll
        for (int e = 0; e < 8; ++e) {
          const int k = 32 * ks + 8 * fg + e;
          unsigned short hs, ls;
          tsplit(wm[ks * 8 + e], hs, ls);
          sW2h[k * 72 + m] = hs;
          sW2l[k * 72 + m] = ls;
        }
      // XA prefetch for next chunk
#pragma unroll
      for (int j = 0; j < 4; ++j)
        xar[j] = XA[cb1 + (4 * fg + j) * 1024 + m];
    }
  }
}

// ---------------------------------------------------------------------------
// Workspace: bXC [0,16.7M) | bXB [16.7M,33.5M) | bZ2b [33.5M,50.3M) | bCo.
// H-split lives in bZ2b region (dead until scan writes); Z2b-split in bXC
// region (dead after scan).  XA lives in d_out until final GEMM overwrites.
// ---------------------------------------------------------------------------
extern "C" void kernel_launch(void* const* d_in, const int* in_sizes, int n_in,
                              void* d_out, int out_size, void* d_ws, size_t ws_size,
                              hipStream_t stream)
{
  const float* H    = (const float*)d_in[0];
  const float* Wq   = (const float*)d_in[1];
  const float* Wk   = (const float*)d_in[2];
  const float* Wv   = (const float*)d_in[3];
  const float* Wo   = (const float*)d_in[4];
  const float* Wil  = (const float*)d_in[5];
  const float* bil  = (const float*)d_in[6];
  const float* W1   = (const float*)d_in[7];
  const float* W2   = (const float*)d_in[8];
  float* out        = (float*)d_out;

  float* ws    = (float*)d_ws;
  float* bXC   = ws;
  float* bXB   = ws + 16777216;
  float* bZ2b  = ws + 33554432;
  float* bCo   = ws + 50331648;
  float* bXA   = out;

  unsigned short* hHi = (unsigned short*)bZ2b;
  unsigned short* hLo = hHi + 16777216;
  unsigned short* zHi = (unsigned short*)bXC;
  unsigned short* zLo = zHi + 16777216;

  const int M = Bsz * Lsz, N = Csz, K = Csz;
  dim3 gm(N / 128, M / 128);
  dim3 bm(256);

  split32<<<16384, 256, 0, stream>>>(H, hHi, hLo);
  gemm_mfma<<<gm, bm, 0, stream>>>(hHi, hLo, Wq, bXC, M, N, K);
  gemm_mfma<<<gm, bm, 0, stream>>>(hHi, hLo, Wk, bXB, M, N, K);
  gemm_mfma<<<gm, bm, 0, stream>>>(hHi, hLo, Wv, bXA, M, N, K);
  ilr_coeff<<<M / 4, 256, 0, stream>>>(H, Wil, bil, bCo);
  ttt_scan<<<Bsz * NHsz, 512, 0, stream>>>(bXA, bXB, bXC, bCo, W1, W2, bZ2b);
  split32<<<16384, 256, 0, stream>>>(bZ2b, zHi, zLo);
  gemm_mfma<<<gm, bm, 0, stream>>>(zHi, zLo, Wo, out, M, N, K);
}

// Round 14
// 8293.632 us; speedup vs baseline: 1.3535x; 1.0308x over previous
//
#include <hip/hip_runtime.h>

#define Bsz  4
#define Lsz  4096
#define Csz  1024
#define NHsz 16
#define CSsz 16
#define HFsz 64
#define HF4sz 256
#define NCsz 256

typedef __attribute__((ext_vector_type(8))) short  bhalf8;
typedef __attribute__((ext_vector_type(4))) float  floatx4;

// ---------------------------------------------------------------------------
// fp32 -> bf16 helpers.  tsplit: trunc-hi + RNE-lo (x ~= h+l, |err|~2^-16|x|).
// ---------------------------------------------------------------------------
__device__ __forceinline__ unsigned short bf_rne(float x) {
  const unsigned u = __float_as_uint(x);
  return (unsigned short)((u + 0x7fffu + ((u >> 16) & 1u)) >> 16);
}
__device__ __forceinline__ void split_rne(float x, unsigned short& h, unsigned short& l) {
  h = bf_rne(x);
  const float hf = __uint_as_float((unsigned)h << 16);
  l = bf_rne(x - hf);
}
__device__ __forceinline__ void tsplit(float x, unsigned short& h, unsigned short& l) {
  const unsigned u = __float_as_uint(x);
  h = (unsigned short)(u >> 16);
  const float r = x - __uint_as_float(u & 0xffff0000u);
  l = bf_rne(r);
}
__device__ __forceinline__ void split_frag8(const float* __restrict__ x,
                                            bhalf8& h, bhalf8& l) {
#pragma unroll
  for (int e = 0; e < 8; ++e) {
    unsigned short hs, ls;
    tsplit(x[e], hs, ls);
    h[e] = (short)hs; l[e] = (short)ls;
  }
}
__device__ __forceinline__ float recon2(unsigned short h, unsigned short l) {
  return __uint_as_float((unsigned)h << 16) + __uint_as_float((unsigned)l << 16);
}

#define MFMA3(acc, ah, al, bh, bl)                                            \
  acc = __builtin_amdgcn_mfma_f32_16x16x32_bf16(ah, bh, acc, 0, 0, 0);        \
  acc = __builtin_amdgcn_mfma_f32_16x16x32_bf16(ah, bl, acc, 0, 0, 0);        \
  acc = __builtin_amdgcn_mfma_f32_16x16x32_bf16(al, bh, acc, 0, 0, 0);

// ---------------------------------------------------------------------------
// bulk fp32 -> split-bf16 (hi[], lo[]) for the big GEMMs (RNE split).
// ---------------------------------------------------------------------------
__global__ __launch_bounds__(256)
void split32(const float* __restrict__ in, unsigned short* __restrict__ hi,
             unsigned short* __restrict__ lo)
{
  const int i = (blockIdx.x * 256 + threadIdx.x) * 4;
  const float4 v = *(const float4*)&in[i];
  ushort4 h, l;
  split_rne(v.x, h.x, l.x);
  split_rne(v.y, h.y, l.y);
  split_rne(v.z, h.z, l.z);
  split_rne(v.w, h.w, l.w);
  *(ushort4*)&hi[i] = h;
  *(ushort4*)&lo[i] = l;
}

// ---------------------------------------------------------------------------
// MFMA GEMM (validated round 9): C = A@B, A pre-split, B fp32 inline-split.
// ---------------------------------------------------------------------------
__global__ __launch_bounds__(256)
void gemm_mfma(const unsigned short* __restrict__ Ahi,
               const unsigned short* __restrict__ Alo,
               const float* __restrict__ Bm,
               float* __restrict__ Cm, int M, int N, int K)
{
  __shared__ unsigned short sAh[128 * 40];
  __shared__ unsigned short sAl[128 * 40];
  __shared__ unsigned short sBh[128 * 40];
  __shared__ unsigned short sBl[128 * 40];

  const int t    = threadIdx.x;
  const int lane = t & 63, w = t >> 6;
  const int wr   = (w >> 1) * 64, wc = (w & 1) * 64;
  const int row0 = blockIdx.y * 128, col0 = blockIdx.x * 128;
  const int fr   = lane & 15, fk = (lane >> 4) * 8;

  floatx4 acc[4][4];
#pragma unroll
  for (int mi = 0; mi < 4; ++mi)
#pragma unroll
    for (int ni = 0; ni < 4; ++ni) acc[mi][ni] = (floatx4){0.f, 0.f, 0.f, 0.f};

  const int arow = t >> 1, akg = (t & 1) * 16;
  const int bc4  = (t & 31) * 4, bk4 = (t >> 5) * 4;

  for (int k0 = 0; k0 < K; k0 += 32) {
    {
      const size_t ga = (size_t)(row0 + arow) * K + k0 + akg;
      const bhalf8 h0 = *(const bhalf8*)&Ahi[ga];
      const bhalf8 h1 = *(const bhalf8*)&Ahi[ga + 8];
      const bhalf8 l0 = *(const bhalf8*)&Alo[ga];
      const bhalf8 l1 = *(const bhalf8*)&Alo[ga + 8];
      *(bhalf8*)&sAh[arow * 40 + akg]     = h0;
      *(bhalf8*)&sAh[arow * 40 + akg + 8] = h1;
      *(bhalf8*)&sAl[arow * 40 + akg]     = l0;
      *(bhalf8*)&sAl[arow * 40 + akg + 8] = l1;
    }
    {
      const float4 r0 = *(const float4*)&Bm[(size_t)(k0 + bk4 + 0) * N + col0 + bc4];
      const float4 r1 = *(const float4*)&Bm[(size_t)(k0 + bk4 + 1) * N + col0 + bc4];
      const float4 r2 = *(const float4*)&Bm[(size_t)(k0 + bk4 + 2) * N + col0 + bc4];
      const float4 r3 = *(const float4*)&Bm[(size_t)(k0 + bk4 + 3) * N + col0 + bc4];
#define STORE_BCOL(v0, v1, v2, v3, c) do {                                   \
      unsigned short h0_, h1_, h2_, h3_, l0_, l1_, l2_, l3_;                 \
      split_rne(v0, h0_, l0_); split_rne(v1, h1_, l1_);                      \
      split_rne(v2, h2_, l2_); split_rne(v3, h3_, l3_);                      \
      const int off_ = (bc4 + (c)) * 40 + bk4;                               \
      *(unsigned*)&sBh[off_]     = (unsigned)h0_ | ((unsigned)h1_ << 16);    \
      *(unsigned*)&sBh[off_ + 2] = (unsigned)h2_ | ((unsigned)h3_ << 16);    \
      *(unsigned*)&sBl[off_]     = (unsigned)l0_ | ((unsigned)l1_ << 16);    \
      *(unsigned*)&sBl[off_ + 2] = (unsigned)l2_ | ((unsigned)l3_ << 16);    \
    } while (0)
      STORE_BCOL(r0.x, r1.x, r2.x, r3.x, 0);
      STORE_BCOL(r0.y, r1.y, r2.y, r3.y, 1);
      STORE_BCOL(r0.z, r1.z, r2.z, r3.z, 2);
      STORE_BCOL(r0.w, r1.w, r2.w, r3.w, 3);
#undef STORE_BCOL
    }
    __syncthreads();

    bhalf8 ah[4], al[4];
#pragma unroll
    for (int mi = 0; mi < 4; ++mi) {
      ah[mi] = *(const bhalf8*)&sAh[(wr + mi * 16 + fr) * 40 + fk];
      al[mi] = *(const bhalf8*)&sAl[(wr + mi * 16 + fr) * 40 + fk];
    }
#pragma unroll
    for (int ni = 0; ni < 4; ++ni) {
      const bhalf8 bh = *(const bhalf8*)&sBh[(wc + ni * 16 + fr) * 40 + fk];
      const bhalf8 bl = *(const bhalf8*)&sBl[(wc + ni * 16 + fr) * 40 + fk];
#pragma unroll
      for (int mi = 0; mi < 4; ++mi) {
        acc[mi][ni] = __builtin_amdgcn_mfma_f32_16x16x32_bf16(ah[mi], bh, acc[mi][ni], 0, 0, 0);
        acc[mi][ni] = __builtin_amdgcn_mfma_f32_16x16x32_bf16(ah[mi], bl, acc[mi][ni], 0, 0, 0);
        acc[mi][ni] = __builtin_amdgcn_mfma_f32_16x16x32_bf16(al[mi], bh, acc[mi][ni], 0, 0, 0);
      }
    }
    __syncthreads();
  }

  const int er = (lane >> 4) * 4;
#pragma unroll
  for (int mi = 0; mi < 4; ++mi)
#pragma unroll
    for (int ni = 0; ni < 4; ++ni) {
      const size_t base = (size_t)(row0 + wr + mi * 16 + er) * N + col0 + wc + ni * 16 + fr;
#pragma unroll
      for (int j = 0; j < 4; ++j)
        Cm[base + (size_t)j * N] = acc[mi][ni][j];
    }
}

// ---------------------------------------------------------------------------
// ilr -> coeff table (unchanged)
// ---------------------------------------------------------------------------
__global__ __launch_bounds__(256)
void ilr_coeff(const float* __restrict__ H, const float* __restrict__ Wil,
               const float* __restrict__ bil, float* __restrict__ coeff)
{
  __shared__ float sRow[4][1024];
  __shared__ float sP[4][16][17];
  const int t = threadIdx.x;
  const size_t r0 = (size_t)blockIdx.x * 4;
  for (int rr = 0; rr < 4; ++rr)
    for (int c = t; c < 1024; c += 256)
      sRow[rr][c] = H[(r0 + rr) * 1024 + c];
  __syncthreads();
  const int hh = t & 15, sl = t >> 4;
  for (int rr = 0; rr < 4; ++rr) {
    float acc = 0.f;
    for (int kk = 0; kk < 64; ++kk)
      acc += sRow[rr][sl * 64 + kk] * Wil[(sl * 64 + kk) * 16 + hh];
    sP[rr][sl][hh] = acc;
  }
  __syncthreads();
  if (t < 64) {
    const int rr = t >> 4, h2 = t & 15;
    float s = 0.f;
    for (int sl2 = 0; sl2 < 16; ++sl2) s += sP[rr][sl2][h2];
    s += bil[h2];
    const float sig = 1.f / (1.f + expf(-s));
    const int r  = (int)(r0 + rr);
    const int b  = r >> 12, l = r & 4095, nc = l >> 4, cs = l & 15;
    coeff[((b * 16 + h2) * NCsz + nc) * CSsz + cs] = sig / ((float)(cs + 1) * 64.0f);
  }
}

// ---------------------------------------------------------------------------
// TTT scan v16 — v15 (overlay, 7.78ms) + zba spilled to LDS deliberately.
//
// Round-13 post-mortem: overlay halved spills (2.12GB -> 981MB = ~27
// dwords/thread/chunk left).  Largest remaining persistent block: zba[4]
// (16 VGPRs, z1bp D-frags, P1'->P5 across 3 barriers) on top of wm[64] +
// P1' temps (~128 peak).  v16 reuses v14's validated dataflow: P1' pass-b
// split-stores z1bp into sZbh/sZbl (buffers dead until P5); P5 recon2s,
// finalizes Z1b, overwrites in place.  Costs 16 tsplit-stores + 16 recon
// reads/chunk — far cheaper than 900MB of scratch round-trips.  (v14's
// regression was doing this WITHOUT the overlay: removed 16 regs against a
// 148-reg union = no spill relief, pure added work.)
// Everything else byte-identical to v15.
// ---------------------------------------------------------------------------
__global__ __launch_bounds__(512)
void ttt_scan(const float* __restrict__ XA, const float* __restrict__ XBuf,
              const float* __restrict__ XCbuf, const float* __restrict__ coeff,
              const float* __restrict__ W1g, const float* __restrict__ W2g,
              float* __restrict__ Out)
{
  __shared__ __attribute__((aligned(16))) unsigned short sW2h[256 * 72]; // 36864
  __shared__ __attribute__((aligned(16))) unsigned short sW2l[256 * 72]; // 36864
  __shared__ __attribute__((aligned(16))) unsigned short sZ1h[16 * 264]; // 8448
  __shared__ __attribute__((aligned(16))) unsigned short sZ1l[16 * 264];
  __shared__ __attribute__((aligned(16))) unsigned short sZbh[16 * 264]; // z1bp | Z1b
  __shared__ __attribute__((aligned(16))) unsigned short sZbl[16 * 264];
  __shared__ __attribute__((aligned(16))) float sZ1t[256 * 20];          // 20480
  __shared__ __attribute__((aligned(16))) float sG1 [256 * 20];          // 20480
  __shared__ __attribute__((aligned(16))) unsigned short sg2h[16 * 72];  // 2304
  __shared__ __attribute__((aligned(16))) unsigned short sg2l[16 * 72];
  __shared__ __attribute__((aligned(16))) float sXBt[64 * 20];           // 5120
  __shared__ __attribute__((aligned(16))) float sA1 [16 * 17];           // 1088
  __shared__ __attribute__((aligned(16))) float sA2p[4 * 16 * 17];       // 4352
  __shared__ __attribute__((aligned(16))) float sCo [2 * 16];            // 128

  const int t    = threadIdx.x;
  const int bh   = blockIdx.x;            // 0..63
  const int b    = bh >> 4, h = bh & 15;
  const bool isA = (t < 256);
  const int lane = t & 63;
  const int fr   = lane & 15, fg = lane >> 4;
  const int w    = t >> 6;                // A: 0..3
  const int tb   = t - 256;               // B local
  const int wb   = (t >> 6) & 3;          // B: 0..3
  const int m    = 16 * wb + fr;          // B: W2 col

  // SHARED overlay: A-threads: wm = W1 frags [tt*16+ks*8+e];
  //                 B-threads: wm = W2 frags [ks*8+e].
  float wm[64];
  floatx4 zb2;     // B: Z2b D-frag  (P6 -> P7)
  float xar[4];    // B: XA prefetch

  const float* W1h = W1g + h * HFsz * HF4sz;
  const float* W2h = W2g + h * HF4sz * HFsz;
  if (isA) {
#pragma unroll
    for (int tt = 0; tt < 4; ++tt)
#pragma unroll
      for (int ks = 0; ks < 2; ++ks)
#pragma unroll
        for (int e = 0; e < 8; ++e)
          wm[tt * 16 + ks * 8 + e] = W1h[(32 * ks + 8 * fg + e) * 256 + (64 * w + 16 * tt + fr)];
  } else {
#pragma unroll
    for (int ks = 0; ks < 8; ++ks)
#pragma unroll
      for (int e = 0; e < 8; ++e)
        wm[ks * 8 + e] = W2h[(32 * ks + 8 * fg + e) * 64 + m];
#pragma unroll
    for (int ks = 0; ks < 8; ++ks)
#pragma unroll
      for (int e = 0; e < 8; ++e) {
        const int k = 32 * ks + 8 * fg + e;
        unsigned short hs, ls;
        tsplit(wm[ks * 8 + e], hs, ls);
        sW2h[k * 72 + m] = hs;
        sW2l[k * 72 + m] = ls;
      }
    const int cb0 = (b * Lsz) * Csz + h * HFsz;
#pragma unroll
    for (int j = 0; j < 4; ++j)
      xar[j] = XA[cb0 + (4 * fg + j) * 1024 + m];
  }
  __syncthreads();

#pragma unroll 1
  for (int nc = 0; nc < NCsz; ++nc) {
    const int cur = nc & 1;
    const int cb  = (b * Lsz + nc * CSsz) * Csz + h * HFsz;
    const int nc1 = (nc + 1) & (NCsz - 1);
    const int cb1 = (b * Lsz + nc1 * CSsz) * Csz + h * HFsz;
    const float* __restrict__ xbG = XBuf  + cb;
    const float* __restrict__ xcG = XCbuf + cb;

    // ========= P1': A: Z1 MFMA + z1bp MFMA (split-stored) | B: Attn1 =====
    if (isA) {
      if (t < 16) sCo[cur * 16 + t] = coeff[(bh * NCsz + nc) * CSsz + t];
      const float* __restrict__ xbp = xbG + fr * 1024 + 8 * fg;
      const float* __restrict__ xcp = xcG + fr * 1024 + 8 * fg;
      // pass a: Z1
      {
        float xv[8];
        bhalf8 xh0, xl0, xh1, xl1;
        *(float4*)&xv[0] = *(const float4*)&xbp[0];
        *(float4*)&xv[4] = *(const float4*)&xbp[4];
        split_frag8(xv, xh0, xl0);
        *(float4*)&xv[0] = *(const float4*)&xbp[32];
        *(float4*)&xv[4] = *(const float4*)&xbp[36];
        split_frag8(xv, xh1, xl1);
#pragma unroll
        for (int tt = 0; tt < 4; ++tt) {
          bhalf8 wh, wl;
          floatx4 acc = (floatx4){0.f, 0.f, 0.f, 0.f};
          split_frag8(&wm[tt * 16], wh, wl);
          MFMA3(acc, xh0, xl0, wh, wl);
          split_frag8(&wm[tt * 16 + 8], wh, wl);
          MFMA3(acc, xh1, xl1, wh, wl);
          const int n = 64 * w + 16 * tt + fr;
#pragma unroll
          for (int j = 0; j < 4; ++j) {
            const int i = 4 * fg + j;
            unsigned short hs, ls; tsplit(acc[j], hs, ls);
            sZ1h[i * 264 + n] = hs;
            sZ1l[i * 264 + n] = ls;
            sZ1t[n * 20 + i]  = acc[j];
          }
        }
      }
      // pass b: z1bp -> split-stored to sZb (regs freed; read back in P5)
      {
        float xv[8];
        bhalf8 xh0, xl0, xh1, xl1;
        *(float4*)&xv[0] = *(const float4*)&xcp[0];
        *(float4*)&xv[4] = *(const float4*)&xcp[4];
        split_frag8(xv, xh0, xl0);
        *(float4*)&xv[0] = *(const float4*)&xcp[32];
        *(float4*)&xv[4] = *(const float4*)&xcp[36];
        split_frag8(xv, xh1, xl1);
#pragma unroll
        for (int tt = 0; tt < 4; ++tt) {
          bhalf8 wh, wl;
          floatx4 acc = (floatx4){0.f, 0.f, 0.f, 0.f};
          split_frag8(&wm[tt * 16], wh, wl);
          MFMA3(acc, xh0, xl0, wh, wl);
          split_frag8(&wm[tt * 16 + 8], wh, wl);
          MFMA3(acc, xh1, xl1, wh, wl);
          const int n = 64 * w + 16 * tt + fr;
#pragma unroll
          for (int j = 0; j < 4; ++j) {
            const int i = 4 * fg + j;
            unsigned short hs, ls; tsplit(acc[j], hs, ls);
            sZbh[i * 264 + n] = hs;
            sZbl[i * 264 + n] = ls;
          }
        }
      }
    } else {
      const int ia = tb >> 4, ja = tb & 15;
      float a0 = 0.f, a1 = 0.f;
      if (ja <= ia) {
#pragma unroll
        for (int k = 0; k < 64; k += 8) {
          const float4 c0 = *(const float4*)&xcG[ia * 1024 + k];
          const float4 b0 = *(const float4*)&xbG[ja * 1024 + k];
          const float4 c1 = *(const float4*)&xcG[ia * 1024 + k + 4];
          const float4 b1 = *(const float4*)&xbG[ja * 1024 + k + 4];
          a0 = fmaf(c0.w, b0.w, fmaf(c0.z, b0.z, fmaf(c0.y, b0.y, fmaf(c0.x, b0.x, a0))));
          a1 = fmaf(c1.w, b1.w, fmaf(c1.z, b1.z, fmaf(c1.y, b1.y, fmaf(c1.x, b1.x, a1))));
        }
      }
      sA1[ia * 17 + ja] = a0 + a1;   // 0 on upper triangle
    }
    __syncthreads();

    // ================= P2': B: Z2 + g2 | A: XBt stage ====================
    if (!isA) {
      floatx4 z2a = (floatx4){0.f, 0.f, 0.f, 0.f};
#pragma unroll
      for (int ks = 0; ks < 8; ++ks) {
        const bhalf8 ah = *(const bhalf8*)&sZ1h[fr * 264 + 32 * ks + 8 * fg];
        const bhalf8 al = *(const bhalf8*)&sZ1l[fr * 264 + 32 * ks + 8 * fg];
        bhalf8 wh, wl; split_frag8(&wm[ks * 8], wh, wl);
        MFMA3(z2a, ah, al, wh, wl);
      }
#pragma unroll
      for (int j = 0; j < 4; ++j) {
        const int i = 4 * fg + j;
        const float g2v = z2a[j] - xar[j];
        unsigned short hs, ls; tsplit(g2v, hs, ls);
        sg2h[i * 72 + m] = hs;
        sg2l[i * 72 + m] = ls;
      }
    } else {
      const int ir = t >> 4, k4 = (t & 15) * 4;
      const float4 v = *(const float4*)&xbG[ir * 1024 + k4];
      sXBt[(k4 + 0) * 20 + ir] = v.x;
      sXBt[(k4 + 1) * 20 + ir] = v.y;
      sXBt[(k4 + 2) * 20 + ir] = v.z;
      sXBt[(k4 + 3) * 20 + ir] = v.w;
    }
    __syncthreads();

    // ================= P4: B: g1^T = W2 @ g2^T (MFMA) -> sG1 =============
    if (!isA) {
      floatx4 g1a[4];
#pragma unroll
      for (int r = 0; r < 4; ++r) g1a[r] = (floatx4){0.f, 0.f, 0.f, 0.f};
#pragma unroll
      for (int ks2 = 0; ks2 < 2; ++ks2) {
        const bhalf8 gh = *(const bhalf8*)&sg2h[fr * 72 + 32 * ks2 + 8 * fg];
        const bhalf8 gl = *(const bhalf8*)&sg2l[fr * 72 + 32 * ks2 + 8 * fg];
#pragma unroll
        for (int r = 0; r < 4; ++r) {
          const int rt = 4 * wb + r;
          const bhalf8 ah = *(const bhalf8*)&sW2h[(16 * rt + fr) * 72 + 32 * ks2 + 8 * fg];
          const bhalf8 al = *(const bhalf8*)&sW2l[(16 * rt + fr) * 72 + 32 * ks2 + 8 * fg];
          MFMA3(g1a[r], ah, al, gh, gl);
        }
      }
#pragma unroll
      for (int r = 0; r < 4; ++r) {
        const int rt = 4 * wb + r;
#pragma unroll
        for (int j = 0; j < 4; ++j)
          sG1[(16 * rt + 4 * fg + j) * 20 + fr] = g1a[r][j];
      }
    }
    __syncthreads();

    // ========= P5: A: Z1b finalize (z1bp from sZb) -> sZb ================
    if (isA) {
#pragma unroll
      for (int tt = 0; tt < 4; ++tt) {
        const int n = 64 * w + 16 * tt + fr;
        float gv[16];
        *(float4*)&gv[0]  = *(const float4*)&sG1[n * 20 + 0];
        *(float4*)&gv[4]  = *(const float4*)&sG1[n * 20 + 4];
        *(float4*)&gv[8]  = *(const float4*)&sG1[n * 20 + 8];
        *(float4*)&gv[12] = *(const float4*)&sG1[n * 20 + 12];
#pragma unroll
        for (int j = 0; j < 4; ++j) {
          const int i = 4 * fg + j;
          float at = 0.f;
#pragma unroll
          for (int jp = 0; jp < 16; ++jp)
            at = fmaf(sA1[i * 17 + jp], gv[jp], at);   // upper tri of A1 is 0
          const float z1bp = recon2(sZbh[i * 264 + n], sZbl[i * 264 + n]);
          const float z = z1bp - sCo[cur * 16 + i] * at;
          unsigned short hs, ls; tsplit(z, hs, ls);
          sZbh[i * 264 + n] = hs;
          sZbl[i * 264 + n] = ls;
        }
      }
    }
    __syncthreads();

    // ========== P6: A: Attn2 K-part MFMA + W1up | B: Z2b + W2up ==========
    if (isA) {
      floatx4 a2 = (floatx4){0.f, 0.f, 0.f, 0.f};
#pragma unroll
      for (int ksl = 0; ksl < 2; ++ksl) {
        const int ks = 2 * w + ksl;
        const bhalf8 ah  = *(const bhalf8*)&sZbh[fr * 264 + 32 * ks + 8 * fg];
        const bhalf8 al  = *(const bhalf8*)&sZbl[fr * 264 + 32 * ks + 8 * fg];
        const bhalf8 bhf = *(const bhalf8*)&sZ1h[fr * 264 + 32 * ks + 8 * fg];
        const bhalf8 blf = *(const bhalf8*)&sZ1l[fr * 264 + 32 * ks + 8 * fg];
        MFMA3(a2, ah, al, bhf, blf);
      }
#pragma unroll
      for (int j = 0; j < 4; ++j) {
        const int i = 4 * fg + j;
        sA2p[w * 272 + i * 17 + fr] = (fr <= i) ? a2[j] : 0.f;
      }
      // W1 update (exact fp32 on masters)
      const float cl = sCo[cur * 16 + 15];
#pragma unroll
      for (int i = 0; i < 16; ++i) {
        float cg[4];
#pragma unroll
        for (int tt = 0; tt < 4; ++tt)
          cg[tt] = cl * sG1[(64 * w + 16 * tt + fr) * 20 + i];
#pragma unroll
        for (int ks = 0; ks < 2; ++ks)
#pragma unroll
          for (int e = 0; e < 8; ++e) {
            const float xb = sXBt[(32 * ks + 8 * fg + e) * 20 + i];
#pragma unroll
            for (int tt = 0; tt < 4; ++tt)
              wm[tt * 16 + ks * 8 + e] = fmaf(-cg[tt], xb, wm[tt * 16 + ks * 8 + e]);
          }
      }
    } else {
      // Z2b (pre-update W2)
      zb2 = (floatx4){0.f, 0.f, 0.f, 0.f};
#pragma unroll
      for (int ks = 0; ks < 8; ++ks) {
        const bhalf8 ah = *(const bhalf8*)&sZbh[fr * 264 + 32 * ks + 8 * fg];
        const bhalf8 al = *(const bhalf8*)&sZbl[fr * 264 + 32 * ks + 8 * fg];
        bhalf8 wh, wl; split_frag8(&wm[ks * 8], wh, wl);
        MFMA3(zb2, ah, al, wh, wl);
      }
      // W2 update (exact fp32 on masters), i-halved (cg[8] + 8 Z1 floats)
      const float cl = sCo[cur * 16 + 15];
#pragma unroll
      for (int half = 0; half < 2; ++half) {
        float cg[8];
#pragma unroll
        for (int ii = 0; ii < 8; ++ii)
          cg[ii] = cl * recon2(sg2h[(half * 8 + ii) * 72 + m],
                               sg2l[(half * 8 + ii) * 72 + m]);
#pragma unroll
        for (int ks = 0; ks < 8; ++ks)
#pragma unroll
          for (int e = 0; e < 8; ++e) {
            const int k = 32 * ks + 8 * fg + e;
            const float4 z0 = *(const float4*)&sZ1t[k * 20 + half * 8 + 0];
            const float4 z1 = *(const float4*)&sZ1t[k * 20 + half * 8 + 4];
            float acc = wm[ks * 8 + e];
            acc = fmaf(-cg[0], z0.x, acc); acc = fmaf(-cg[1], z0.y, acc);
            acc = fmaf(-cg[2], z0.z, acc); acc = fmaf(-cg[3], z0.w, acc);
            acc = fmaf(-cg[4], z1.x, acc); acc = fmaf(-cg[5], z1.y, acc);
            acc = fmaf(-cg[6], z1.z, acc); acc = fmaf(-cg[7], z1.w, acc);
            wm[ks * 8 + e] = acc;
          }
      }
    }
    __syncthreads();

    // ====== P7: B: Z2b apply + store, sW2 rebuild, XA prefetch ===========
    //  (no trailing barrier: A's next P1' writes sZ1h/l, sZ1t, sZbh/l,
    //   sCo[cur^1] — none of which P7 reads)
    if (!isA) {
      float at[4] = {0.f, 0.f, 0.f, 0.f};
#pragma unroll
      for (int jp = 0; jp < 16; ++jp) {
        const float g2v = recon2(sg2h[jp * 72 + m], sg2l[jp * 72 + m]);
#pragma unroll
        for (int j = 0; j < 4; ++j) {
          const int i = 4 * fg + j;
          const float a2s = sA2p[i * 17 + jp] + sA2p[272 + i * 17 + jp]
                          + sA2p[544 + i * 17 + jp] + sA2p[816 + i * 17 + jp];
          at[j] = fmaf(a2s, g2v, at[j]);
        }
      }
#pragma unroll
      for (int j = 0; j < 4; ++j) {
        const int i = 4 * fg + j;
        Out[cb + i * 1024 + m] = zb2[j] - sCo[cur * 16 + i] * at[j];
      }
      // rebuild split W2 for next chunk's g1
#pragma unroll
      for (int ks = 0; ks < 8; ++ks)
#pragma unroll
        for (int e = 0; e < 8; ++e) {
          const int k = 32 * ks + 8 * fg + e;
          unsigned short hs, ls;
          tsplit(wm[ks * 8 + e], hs, ls);
          sW2h[k * 72 + m] = hs;
          sW2l[k * 72 + m] = ls;
        }
      // XA prefetch for next chunk
#pragma unroll
      for (int j = 0; j < 4; ++j)
        xar[j] = XA[cb1 + (4 * fg + j) * 1024 + m];
    }
  }
}

// ---------------------------------------------------------------------------
// Workspace: bXC [0,16.7M) | bXB [16.7M,33.5M) | bZ2b [33.5M,50.3M) | bCo.
// H-split lives in bZ2b region (dead until scan writes); Z2b-split in bXC
// region (dead after scan).  XA lives in d_out until final GEMM overwrites.
// ---------------------------------------------------------------------------
extern "C" void kernel_launch(void* const* d_in, const int* in_sizes, int n_in,
                              void* d_out, int out_size, void* d_ws, size_t ws_size,
                              hipStream_t stream)
{
  const float* H    = (const float*)d_in[0];
  const float* Wq   = (const float*)d_in[1];
  const float* Wk   = (const float*)d_in[2];
  const float* Wv   = (const float*)d_in[3];
  const float* Wo   = (const float*)d_in[4];
  const float* Wil  = (const float*)d_in[5];
  const float* bil  = (const float*)d_in[6];
  const float* W1   = (const float*)d_in[7];
  const float* W2   = (const float*)d_in[8];
  float* out        = (float*)d_out;

  float* ws    = (float*)d_ws;
  float* bXC   = ws;
  float* bXB   = ws + 16777216;
  float* bZ2b  = ws + 33554432;
  float* bCo   = ws + 50331648;
  float* bXA   = out;

  unsigned short* hHi = (unsigned short*)bZ2b;
  unsigned short* hLo = hHi + 16777216;
  unsigned short* zHi = (unsigned short*)bXC;
  unsigned short* zLo = zHi + 16777216;

  const int M = Bsz * Lsz, N = Csz, K = Csz;
  dim3 gm(N / 128, M / 128);
  dim3 bm(256);

  split32<<<16384, 256, 0, stream>>>(H, hHi, hLo);
  gemm_mfma<<<gm, bm, 0, stream>>>(hHi, hLo, Wq, bXC, M, N, K);
  gemm_mfma<<<gm, bm, 0, stream>>>(hHi, hLo, Wk, bXB, M, N, K);
  gemm_mfma<<<gm, bm, 0, stream>>>(hHi, hLo, Wv, bXA, M, N, K);
  ilr_coeff<<<M / 4, 256, 0, stream>>>(H, Wil, bil, bCo);
  ttt_scan<<<Bsz * NHsz, 512, 0, stream>>>(bXA, bXB, bXC, bCo, W1, W2, bZ2b);
  split32<<<16384, 256, 0, stream>>>(bZ2b, zHi, zLo);
  gemm_mfma<<<gm, bm, 0, stream>>>(zHi, zLo, Wo, out, M, N, K);
}

// Round 16
// 7844.309 us; speedup vs baseline: 1.4310x; 1.0573x over previous
//
#include <hip/hip_runtime.h>

#define Bsz  4
#define Lsz  4096
#define Csz  1024
#define NHsz 16
#define CSsz 16
#define HFsz 64
#define HF4sz 256
#define NCsz 256

typedef __attribute__((ext_vector_type(8))) short  bhalf8;
typedef __attribute__((ext_vector_type(4))) float  floatx4;

// ---------------------------------------------------------------------------
// fp32 -> bf16 helpers.  tsplit: trunc-hi + RNE-lo (x ~= h+l, |err|~2^-16|x|).
// ---------------------------------------------------------------------------
__device__ __forceinline__ unsigned short bf_rne(float x) {
  const unsigned u = __float_as_uint(x);
  return (unsigned short)((u + 0x7fffu + ((u >> 16) & 1u)) >> 16);
}
__device__ __forceinline__ void split_rne(float x, unsigned short& h, unsigned short& l) {
  h = bf_rne(x);
  const float hf = __uint_as_float((unsigned)h << 16);
  l = bf_rne(x - hf);
}
__device__ __forceinline__ void tsplit(float x, unsigned short& h, unsigned short& l) {
  const unsigned u = __float_as_uint(x);
  h = (unsigned short)(u >> 16);
  const float r = x - __uint_as_float(u & 0xffff0000u);
  l = bf_rne(r);
}
__device__ __forceinline__ void split_frag8(const float* __restrict__ x,
                                            bhalf8& h, bhalf8& l) {
#pragma unroll
  for (int e = 0; e < 8; ++e) {
    unsigned short hs, ls;
    tsplit(x[e], hs, ls);
    h[e] = (short)hs; l[e] = (short)ls;
  }
}
__device__ __forceinline__ float recon2(unsigned short h, unsigned short l) {
  return __uint_as_float((unsigned)h << 16) + __uint_as_float((unsigned)l << 16);
}

#define MFMA3(acc, ah, al, bh, bl)                                            \
  acc = __builtin_amdgcn_mfma_f32_16x16x32_bf16(ah, bh, acc, 0, 0, 0);        \
  acc = __builtin_amdgcn_mfma_f32_16x16x32_bf16(ah, bl, acc, 0, 0, 0);        \
  acc = __builtin_amdgcn_mfma_f32_16x16x32_bf16(al, bh, acc, 0, 0, 0);

// ---------------------------------------------------------------------------
// bulk fp32 -> split-bf16 (hi[], lo[]) for the big GEMMs (RNE split).
// ---------------------------------------------------------------------------
__global__ __launch_bounds__(256)
void split32(const float* __restrict__ in, unsigned short* __restrict__ hi,
             unsigned short* __restrict__ lo)
{
  const int i = (blockIdx.x * 256 + threadIdx.x) * 4;
  const float4 v = *(const float4*)&in[i];
  ushort4 h, l;
  split_rne(v.x, h.x, l.x);
  split_rne(v.y, h.y, l.y);
  split_rne(v.z, h.z, l.z);
  split_rne(v.w, h.w, l.w);
  *(ushort4*)&hi[i] = h;
  *(ushort4*)&lo[i] = l;
}

// ---------------------------------------------------------------------------
// MFMA GEMM (validated round 9): C = A@B, A pre-split, B fp32 inline-split.
// ---------------------------------------------------------------------------
__global__ __launch_bounds__(256)
void gemm_mfma(const unsigned short* __restrict__ Ahi,
               const unsigned short* __restrict__ Alo,
               const float* __restrict__ Bm,
               float* __restrict__ Cm, int M, int N, int K)
{
  __shared__ unsigned short sAh[128 * 40];
  __shared__ unsigned short sAl[128 * 40];
  __shared__ unsigned short sBh[128 * 40];
  __shared__ unsigned short sBl[128 * 40];

  const int t    = threadIdx.x;
  const int lane = t & 63, w = t >> 6;
  const int wr   = (w >> 1) * 64, wc = (w & 1) * 64;
  const int row0 = blockIdx.y * 128, col0 = blockIdx.x * 128;
  const int fr   = lane & 15, fk = (lane >> 4) * 8;

  floatx4 acc[4][4];
#pragma unroll
  for (int mi = 0; mi < 4; ++mi)
#pragma unroll
    for (int ni = 0; ni < 4; ++ni) acc[mi][ni] = (floatx4){0.f, 0.f, 0.f, 0.f};

  const int arow = t >> 1, akg = (t & 1) * 16;
  const int bc4  = (t & 31) * 4, bk4 = (t >> 5) * 4;

  for (int k0 = 0; k0 < K; k0 += 32) {
    {
      const size_t ga = (size_t)(row0 + arow) * K + k0 + akg;
      const bhalf8 h0 = *(const bhalf8*)&Ahi[ga];
      const bhalf8 h1 = *(const bhalf8*)&Ahi[ga + 8];
      const bhalf8 l0 = *(const bhalf8*)&Alo[ga];
      const bhalf8 l1 = *(const bhalf8*)&Alo[ga + 8];
      *(bhalf8*)&sAh[arow * 40 + akg]     = h0;
      *(bhalf8*)&sAh[arow * 40 + akg + 8] = h1;
      *(bhalf8*)&sAl[arow * 40 + akg]     = l0;
      *(bhalf8*)&sAl[arow * 40 + akg + 8] = l1;
    }
    {
      const float4 r0 = *(const float4*)&Bm[(size_t)(k0 + bk4 + 0) * N + col0 + bc4];
      const float4 r1 = *(const float4*)&Bm[(size_t)(k0 + bk4 + 1) * N + col0 + bc4];
      const float4 r2 = *(const float4*)&Bm[(size_t)(k0 + bk4 + 2) * N + col0 + bc4];
      const float4 r3 = *(const float4*)&Bm[(size_t)(k0 + bk4 + 3) * N + col0 + bc4];
#define STORE_BCOL(v0, v1, v2, v3, c) do {                                   \
      unsigned short h0_, h1_, h2_, h3_, l0_, l1_, l2_, l3_;                 \
      split_rne(v0, h0_, l0_); split_rne(v1, h1_, l1_);                      \
      split_rne(v2, h2_, l2_); split_rne(v3, h3_, l3_);                      \
      const int off_ = (bc4 + (c)) * 40 + bk4;                               \
      *(unsigned*)&sBh[off_]     = (unsigned)h0_ | ((unsigned)h1_ << 16);    \
      *(unsigned*)&sBh[off_ + 2] = (unsigned)h2_ | ((unsigned)h3_ << 16);    \
      *(unsigned*)&sBl[off_]     = (unsigned)l0_ | ((unsigned)l1_ << 16);    \
      *(unsigned*)&sBl[off_ + 2] = (unsigned)l2_ | ((unsigned)l3_ << 16);    \
    } while (0)
      STORE_BCOL(r0.x, r1.x, r2.x, r3.x, 0);
      STORE_BCOL(r0.y, r1.y, r2.y, r3.y, 1);
      STORE_BCOL(r0.z, r1.z, r2.z, r3.z, 2);
      STORE_BCOL(r0.w, r1.w, r2.w, r3.w, 3);
#undef STORE_BCOL
    }
    __syncthreads();

    bhalf8 ah[4], al[4];
#pragma unroll
    for (int mi = 0; mi < 4; ++mi) {
      ah[mi] = *(const bhalf8*)&sAh[(wr + mi * 16 + fr) * 40 + fk];
      al[mi] = *(const bhalf8*)&sAl[(wr + mi * 16 + fr) * 40 + fk];
    }
#pragma unroll
    for (int ni = 0; ni < 4; ++ni) {
      const bhalf8 bh = *(const bhalf8*)&sBh[(wc + ni * 16 + fr) * 40 + fk];
      const bhalf8 bl = *(const bhalf8*)&sBl[(wc + ni * 16 + fr) * 40 + fk];
#pragma unroll
      for (int mi = 0; mi < 4; ++mi) {
        acc[mi][ni] = __builtin_amdgcn_mfma_f32_16x16x32_bf16(ah[mi], bh, acc[mi][ni], 0, 0, 0);
        acc[mi][ni] = __builtin_amdgcn_mfma_f32_16x16x32_bf16(ah[mi], bl, acc[mi][ni], 0, 0, 0);
        acc[mi][ni] = __builtin_amdgcn_mfma_f32_16x16x32_bf16(al[mi], bh, acc[mi][ni], 0, 0, 0);
      }
    }
    __syncthreads();
  }

  const int er = (lane >> 4) * 4;
#pragma unroll
  for (int mi = 0; mi < 4; ++mi)
#pragma unroll
    for (int ni = 0; ni < 4; ++ni) {
      const size_t base = (size_t)(row0 + wr + mi * 16 + er) * N + col0 + wc + ni * 16 + fr;
#pragma unroll
      for (int j = 0; j < 4; ++j)
        Cm[base + (size_t)j * N] = acc[mi][ni][j];
    }
}

// ---------------------------------------------------------------------------
// ilr -> coeff table (unchanged)
// ---------------------------------------------------------------------------
__global__ __launch_bounds__(256)
void ilr_coeff(const float* __restrict__ H, const float* __restrict__ Wil,
               const float* __restrict__ bil, float* __restrict__ coeff)
{
  __shared__ float sRow[4][1024];
  __shared__ float sP[4][16][17];
  const int t = threadIdx.x;
  const size_t r0 = (size_t)blockIdx.x * 4;
  for (int rr = 0; rr < 4; ++rr)
    for (int c = t; c < 1024; c += 256)
      sRow[rr][c] = H[(r0 + rr) * 1024 + c];
  __syncthreads();
  const int hh = t & 15, sl = t >> 4;
  for (int rr = 0; rr < 4; ++rr) {
    float acc = 0.f;
    for (int kk = 0; kk < 64; ++kk)
      acc += sRow[rr][sl * 64 + kk] * Wil[(sl * 64 + kk) * 16 + hh];
    sP[rr][sl][hh] = acc;
  }
  __syncthreads();
  if (t < 64) {
    const int rr = t >> 4, h2 = t & 15;
    float s = 0.f;
    for (int sl2 = 0; sl2 < 16; ++sl2) s += sP[rr][sl2][h2];
    s += bil[h2];
    const float sig = 1.f / (1.f + expf(-s));
    const int r  = (int)(r0 + rr);
    const int b  = r >> 12, l = r & 4095, nc = l >> 4, cs = l & 15;
    coeff[((b * 16 + h2) * NCsz + nc) * CSsz + cs] = sig / ((float)(cs + 1) * 64.0f);
  }
}

// ---------------------------------------------------------------------------
// TTT scan v17 (resubmission — round-15 bench died to an infra failure,
// UnresponsiveContainer, before producing any data).
// v17 = v16 (7.50ms) + the two COUNTER-VALIDATED v13 layout fixes
// (conflicts 129M -> 33M in v13; v13's regression was its z1bp phase move,
// not these):
//  (1) sZ1t fg-XOR swizzle: write float4 at n*20+((fg^((n>>3)&3))<<2);
//      P6-B W2-update reads quad q at k*20+((q^fg)<<2) (reader's
//      (k>>3)&3 == fg, so write/read permutations match).  Kills the
//      structural 4-way conflict (8-row k-steps * any 4-dword stride
//      ≡ 0 mod 32 banks).
//  (2) sXBt row-major [16][68]: direct float4 copy in, conflict-free
//      broadcast scalar reads in P6-A (8fg spread across banks). -768B LDS.
// Everything else byte-identical to v16.
// ---------------------------------------------------------------------------
__global__ __launch_bounds__(512)
void ttt_scan(const float* __restrict__ XA, const float* __restrict__ XBuf,
              const float* __restrict__ XCbuf, const float* __restrict__ coeff,
              const float* __restrict__ W1g, const float* __restrict__ W2g,
              float* __restrict__ Out)
{
  __shared__ __attribute__((aligned(16))) unsigned short sW2h[256 * 72]; // 36864
  __shared__ __attribute__((aligned(16))) unsigned short sW2l[256 * 72]; // 36864
  __shared__ __attribute__((aligned(16))) unsigned short sZ1h[16 * 264]; // 8448
  __shared__ __attribute__((aligned(16))) unsigned short sZ1l[16 * 264];
  __shared__ __attribute__((aligned(16))) unsigned short sZbh[16 * 264]; // z1bp | Z1b
  __shared__ __attribute__((aligned(16))) unsigned short sZbl[16 * 264];
  __shared__ __attribute__((aligned(16))) float sZ1t[256 * 20];          // 20480 (fg-XOR blocks)
  __shared__ __attribute__((aligned(16))) float sG1 [256 * 20];          // 20480
  __shared__ __attribute__((aligned(16))) unsigned short sg2h[16 * 72];  // 2304
  __shared__ __attribute__((aligned(16))) unsigned short sg2l[16 * 72];
  __shared__ __attribute__((aligned(16))) float sXBt[16 * 68];           // 4352 row-major
  __shared__ __attribute__((aligned(16))) float sA1 [16 * 17];           // 1088
  __shared__ __attribute__((aligned(16))) float sA2p[4 * 16 * 17];       // 4352
  __shared__ __attribute__((aligned(16))) float sCo [2 * 16];            // 128

  const int t    = threadIdx.x;
  const int bh   = blockIdx.x;            // 0..63
  const int b    = bh >> 4, h = bh & 15;
  const bool isA = (t < 256);
  const int lane = t & 63;
  const int fr   = lane & 15, fg = lane >> 4;
  const int w    = t >> 6;                // A: 0..3
  const int tb   = t - 256;               // B local
  const int wb   = (t >> 6) & 3;          // B: 0..3
  const int m    = 16 * wb + fr;          // B: W2 col

  // SHARED overlay: A-threads: wm = W1 frags [tt*16+ks*8+e];
  //                 B-threads: wm = W2 frags [ks*8+e].
  float wm[64];
  floatx4 zb2;     // B: Z2b D-frag  (P6 -> P7)
  float xar[4];    // B: XA prefetch

  const float* W1h = W1g + h * HFsz * HF4sz;
  const float* W2h = W2g + h * HF4sz * HFsz;
  if (isA) {
#pragma unroll
    for (int tt = 0; tt < 4; ++tt)
#pragma unroll
      for (int ks = 0; ks < 2; ++ks)
#pragma unroll
        for (int e = 0; e < 8; ++e)
          wm[tt * 16 + ks * 8 + e] = W1h[(32 * ks + 8 * fg + e) * 256 + (64 * w + 16 * tt + fr)];
  } else {
#pragma unroll
    for (int ks = 0; ks < 8; ++ks)
#pragma unroll
      for (int e = 0; e < 8; ++e)
        wm[ks * 8 + e] = W2h[(32 * ks + 8 * fg + e) * 64 + m];
#pragma unroll
    for (int ks = 0; ks < 8; ++ks)
#pragma unroll
      for (int e = 0; e < 8; ++e) {
        const int k = 32 * ks + 8 * fg + e;
        unsigned short hs, ls;
        tsplit(wm[ks * 8 + e], hs, ls);
        sW2h[k * 72 + m] = hs;
        sW2l[k * 72 + m] = ls;
      }
    const int cb0 = (b * Lsz) * Csz + h * HFsz;
#pragma unroll
    for (int j = 0; j < 4; ++j)
      xar[j] = XA[cb0 + (4 * fg + j) * 1024 + m];
  }
  __syncthreads();

#pragma unroll 1
  for (int nc = 0; nc < NCsz; ++nc) {
    const int cur = nc & 1;
    const int cb  = (b * Lsz + nc * CSsz) * Csz + h * HFsz;
    const int nc1 = (nc + 1) & (NCsz - 1);
    const int cb1 = (b * Lsz + nc1 * CSsz) * Csz + h * HFsz;
    const float* __restrict__ xbG = XBuf  + cb;
    const float* __restrict__ xcG = XCbuf + cb;

    // ========= P1': A: Z1 MFMA + z1bp MFMA (split-stored) | B: Attn1 =====
    if (isA) {
      if (t < 16) sCo[cur * 16 + t] = coeff[(bh * NCsz + nc) * CSsz + t];
      const float* __restrict__ xbp = xbG + fr * 1024 + 8 * fg;
      const float* __restrict__ xcp = xcG + fr * 1024 + 8 * fg;
      // pass a: Z1
      {
        float xv[8];
        bhalf8 xh0, xl0, xh1, xl1;
        *(float4*)&xv[0] = *(const float4*)&xbp[0];
        *(float4*)&xv[4] = *(const float4*)&xbp[4];
        split_frag8(xv, xh0, xl0);
        *(float4*)&xv[0] = *(const float4*)&xbp[32];
        *(float4*)&xv[4] = *(const float4*)&xbp[36];
        split_frag8(xv, xh1, xl1);
#pragma unroll
        for (int tt = 0; tt < 4; ++tt) {
          bhalf8 wh, wl;
          floatx4 acc = (floatx4){0.f, 0.f, 0.f, 0.f};
          split_frag8(&wm[tt * 16], wh, wl);
          MFMA3(acc, xh0, xl0, wh, wl);
          split_frag8(&wm[tt * 16 + 8], wh, wl);
          MFMA3(acc, xh1, xl1, wh, wl);
          const int n = 64 * w + 16 * tt + fr;
#pragma unroll
          for (int j = 0; j < 4; ++j) {
            const int i = 4 * fg + j;
            unsigned short hs, ls; tsplit(acc[j], hs, ls);
            sZ1h[i * 264 + n] = hs;
            sZ1l[i * 264 + n] = ls;
          }
          const int rotn = (n >> 3) & 3;
          *(float4*)&sZ1t[n * 20 + ((fg ^ rotn) << 2)] = *(float4*)&acc;
        }
      }
      // pass b: z1bp -> split-stored to sZb (regs freed; read back in P5)
      {
        float xv[8];
        bhalf8 xh0, xl0, xh1, xl1;
        *(float4*)&xv[0] = *(const float4*)&xcp[0];
        *(float4*)&xv[4] = *(const float4*)&xcp[4];
        split_frag8(xv, xh0, xl0);
        *(float4*)&xv[0] = *(const float4*)&xcp[32];
        *(float4*)&xv[4] = *(const float4*)&xcp[36];
        split_frag8(xv, xh1, xl1);
#pragma unroll
        for (int tt = 0; tt < 4; ++tt) {
          bhalf8 wh, wl;
          floatx4 acc = (floatx4){0.f, 0.f, 0.f, 0.f};
          split_frag8(&wm[tt * 16], wh, wl);
          MFMA3(acc, xh0, xl0, wh, wl);
          split_frag8(&wm[tt * 16 + 8], wh, wl);
          MFMA3(acc, xh1, xl1, wh, wl);
          const int n = 64 * w + 16 * tt + fr;
#pragma unroll
          for (int j = 0; j < 4; ++j) {
            const int i = 4 * fg + j;
            unsigned short hs, ls; tsplit(acc[j], hs, ls);
            sZbh[i * 264 + n] = hs;
            sZbl[i * 264 + n] = ls;
          }
        }
      }
    } else {
      const int ia = tb >> 4, ja = tb & 15;
      float a0 = 0.f, a1 = 0.f;
      if (ja <= ia) {
#pragma unroll
        for (int k = 0; k < 64; k += 8) {
          const float4 c0 = *(const float4*)&xcG[ia * 1024 + k];
          const float4 b0 = *(const float4*)&xbG[ja * 1024 + k];
          const float4 c1 = *(const float4*)&xcG[ia * 1024 + k + 4];
          const float4 b1 = *(const float4*)&xbG[ja * 1024 + k + 4];
          a0 = fmaf(c0.w, b0.w, fmaf(c0.z, b0.z, fmaf(c0.y, b0.y, fmaf(c0.x, b0.x, a0))));
          a1 = fmaf(c1.w, b1.w, fmaf(c1.z, b1.z, fmaf(c1.y, b1.y, fmaf(c1.x, b1.x, a1))));
        }
      }
      sA1[ia * 17 + ja] = a0 + a1;   // 0 on upper triangle
    }
    __syncthreads();

    // ================= P2': B: Z2 + g2 | A: XBt stage ====================
    if (!isA) {
      floatx4 z2a = (floatx4){0.f, 0.f, 0.f, 0.f};
#pragma unroll
      for (int ks = 0; ks < 8; ++ks) {
        const bhalf8 ah = *(const bhalf8*)&sZ1h[fr * 264 + 32 * ks + 8 * fg];
        const bhalf8 al = *(const bhalf8*)&sZ1l[fr * 264 + 32 * ks + 8 * fg];
        bhalf8 wh, wl; split_frag8(&wm[ks * 8], wh, wl);
        MFMA3(z2a, ah, al, wh, wl);
      }
#pragma unroll
      for (int j = 0; j < 4; ++j) {
        const int i = 4 * fg + j;
        const float g2v = z2a[j] - xar[j];
        unsigned short hs, ls; tsplit(g2v, hs, ls);
        sg2h[i * 72 + m] = hs;
        sg2l[i * 72 + m] = ls;
      }
    } else {
      const int ir = t >> 4, k4 = (t & 15) * 4;
      *(float4*)&sXBt[ir * 68 + k4] = *(const float4*)&xbG[ir * 1024 + k4];
    }
    __syncthreads();

    // ================= P4: B: g1^T = W2 @ g2^T (MFMA) -> sG1 =============
    if (!isA) {
      floatx4 g1a[4];
#pragma unroll
      for (int r = 0; r < 4; ++r) g1a[r] = (floatx4){0.f, 0.f, 0.f, 0.f};
#pragma unroll
      for (int ks2 = 0; ks2 < 2; ++ks2) {
        const bhalf8 gh = *(const bhalf8*)&sg2h[fr * 72 + 32 * ks2 + 8 * fg];
        const bhalf8 gl = *(const bhalf8*)&sg2l[fr * 72 + 32 * ks2 + 8 * fg];
#pragma unroll
        for (int r = 0; r < 4; ++r) {
          const int rt = 4 * wb + r;
          const bhalf8 ah = *(const bhalf8*)&sW2h[(16 * rt + fr) * 72 + 32 * ks2 + 8 * fg];
          const bhalf8 al = *(const bhalf8*)&sW2l[(16 * rt + fr) * 72 + 32 * ks2 + 8 * fg];
          MFMA3(g1a[r], ah, al, gh, gl);
        }
      }
#pragma unroll
      for (int r = 0; r < 4; ++r) {
        const int rt = 4 * wb + r;
#pragma unroll
        for (int j = 0; j < 4; ++j)
          sG1[(16 * rt + 4 * fg + j) * 20 + fr] = g1a[r][j];
      }
    }
    __syncthreads();

    // ========= P5: A: Z1b finalize (z1bp from sZb) -> sZb ================
    if (isA) {
#pragma unroll
      for (int tt = 0; tt < 4; ++tt) {
        const int n = 64 * w + 16 * tt + fr;
        float gv[16];
        *(float4*)&gv[0]  = *(const float4*)&sG1[n * 20 + 0];
        *(float4*)&gv[4]  = *(const float4*)&sG1[n * 20 + 4];
        *(float4*)&gv[8]  = *(const float4*)&sG1[n * 20 + 8];
        *(float4*)&gv[12] = *(const float4*)&sG1[n * 20 + 12];
#pragma unroll
        for (int j = 0; j < 4; ++j) {
          const int i = 4 * fg + j;
          float at = 0.f;
#pragma unroll
          for (int jp = 0; jp < 16; ++jp)
            at = fmaf(sA1[i * 17 + jp], gv[jp], at);   // upper tri of A1 is 0
          const float z1bp = recon2(sZbh[i * 264 + n], sZbl[i * 264 + n]);
          const float z = z1bp - sCo[cur * 16 + i] * at;
          unsigned short hs, ls; tsplit(z, hs, ls);
          sZbh[i * 264 + n] = hs;
          sZbl[i * 264 + n] = ls;
        }
      }
    }
    __syncthreads();

    // ========== P6: A: Attn2 K-part MFMA + W1up | B: Z2b + W2up ==========
    if (isA) {
      floatx4 a2 = (floatx4){0.f, 0.f, 0.f, 0.f};
#pragma unroll
      for (int ksl = 0; ksl < 2; ++ksl) {
        const int ks = 2 * w + ksl;
        const bhalf8 ah  = *(const bhalf8*)&sZbh[fr * 264 + 32 * ks + 8 * fg];
        const bhalf8 al  = *(const bhalf8*)&sZbl[fr * 264 + 32 * ks + 8 * fg];
        const bhalf8 bhf = *(const bhalf8*)&sZ1h[fr * 264 + 32 * ks + 8 * fg];
        const bhalf8 blf = *(const bhalf8*)&sZ1l[fr * 264 + 32 * ks + 8 * fg];
        MFMA3(a2, ah, al, bhf, blf);
      }
#pragma unroll
      for (int j = 0; j < 4; ++j) {
        const int i = 4 * fg + j;
        sA2p[w * 272 + i * 17 + fr] = (fr <= i) ? a2[j] : 0.f;
      }
      // W1 update (exact fp32 on masters); sXBt row-major broadcast reads
      const float cl = sCo[cur * 16 + 15];
#pragma unroll
      for (int i = 0; i < 16; ++i) {
        float cg[4];
#pragma unroll
        for (int tt = 0; tt < 4; ++tt)
          cg[tt] = cl * sG1[(64 * w + 16 * tt + fr) * 20 + i];
#pragma unroll
        for (int ks = 0; ks < 2; ++ks)
#pragma unroll
          for (int e = 0; e < 8; ++e) {
            const float xb = sXBt[i * 68 + 32 * ks + 8 * fg + e];
#pragma unroll
            for (int tt = 0; tt < 4; ++tt)
              wm[tt * 16 + ks * 8 + e] = fmaf(-cg[tt], xb, wm[tt * 16 + ks * 8 + e]);
          }
      }
    } else {
      // Z2b (pre-update W2)
      zb2 = (floatx4){0.f, 0.f, 0.f, 0.f};
#pragma unroll
      for (int ks = 0; ks < 8; ++ks) {
        const bhalf8 ah = *(const bhalf8*)&sZbh[fr * 264 + 32 * ks + 8 * fg];
        const bhalf8 al = *(const bhalf8*)&sZbl[fr * 264 + 32 * ks + 8 * fg];
        bhalf8 wh, wl; split_frag8(&wm[ks * 8], wh, wl);
        MFMA3(zb2, ah, al, wh, wl);
      }
      // W2 update (exact fp32 on masters), i-halved; sZ1t fg-XOR reads
      const float cl = sCo[cur * 16 + 15];
#pragma unroll
      for (int half = 0; half < 2; ++half) {
        float cg[8];
#pragma unroll
        for (int ii = 0; ii < 8; ++ii)
          cg[ii] = cl * recon2(sg2h[(half * 8 + ii) * 72 + m],
                               sg2l[(half * 8 + ii) * 72 + m]);
#pragma unroll
        for (int ks = 0; ks < 8; ++ks)
#pragma unroll
          for (int e = 0; e < 8; ++e) {
            const int k = 32 * ks + 8 * fg + e;
            const float4 z0 = *(const float4*)&sZ1t[k * 20 + (((2 * half + 0) ^ fg) << 2)];
            const float4 z1 = *(const float4*)&sZ1t[k * 20 + (((2 * half + 1) ^ fg) << 2)];
            float acc = wm[ks * 8 + e];
            acc = fmaf(-cg[0], z0.x, acc); acc = fmaf(-cg[1], z0.y, acc);
            acc = fmaf(-cg[2], z0.z, acc); acc = fmaf(-cg[3], z0.w, acc);
            acc = fmaf(-cg[4], z1.x, acc); acc = fmaf(-cg[5], z1.y, acc);
            acc = fmaf(-cg[6], z1.z, acc); acc = fmaf(-cg[7], z1.w, acc);
            wm[ks * 8 + e] = acc;
          }
      }
    }
    __syncthreads();

    // ====== P7: B: Z2b apply + store, sW2 rebuild, XA prefetch ===========
    //  (no trailing barrier: A's next P1' writes sZ1h/l, sZ1t, sZbh/l,
    //   sCo[cur^1] — none of which P7 reads)
    if (!isA) {
      float at[4] = {0.f, 0.f, 0.f, 0.f};
#pragma unroll
      for (int jp = 0; jp < 16; ++jp) {
        const float g2v = recon2(sg2h[jp * 72 + m], sg2l[jp * 72 + m]);
#pragma unroll
        for (int j = 0; j < 4; ++j) {
          const int i = 4 * fg + j;
          const float a2s = sA2p[i * 17 + jp] + sA2p[272 + i * 17 + jp]
                          + sA2p[544 + i * 17 + jp] + sA2p[816 + i * 17 + jp];
          at[j] = fmaf(a2s, g2v, at[j]);
        }
      }
#pragma unroll
      for (int j = 0; j < 4; ++j) {
        const int i = 4 * fg + j;
        Out[cb + i * 1024 + m] = zb2[j] - sCo[cur * 16 + i] * at[j];
      }
      // rebuild split W2 for next chunk's g1
#pragma unroll
      for (int ks = 0; ks < 8; ++ks)
#pragma unroll
        for (int e = 0; e < 8; ++e) {
          const int k = 32 * ks + 8 * fg + e;
          unsigned short hs, ls;
          tsplit(wm[ks * 8 + e], hs, ls);
          sW2h[k * 72 + m] = hs;
          sW2l[k * 72 + m] = ls;
        }
      // XA prefetch for next chunk
#pragma unroll
      for (int j = 0; j < 4; ++j)
        xar[j] = XA[cb1 + (4 * fg + j) * 1024 + m];
    }
  }
}

// ---------------------------------------------------------------------------
// Workspace: bXC [0,16.7M) | bXB [16.7M,33.5M) | bZ2b [33.5M,50.3M) | bCo.
// H-split lives in bZ2b region (dead until scan writes); Z2b-split in bXC
// region (dead after scan).  XA lives in d_out until final GEMM overwrites.
// ---------------------------------------------------------------------------
extern "C" void kernel_launch(void* const* d_in, const int* in_sizes, int n_in,
                              void* d_out, int out_size, void* d_ws, size_t ws_size,
                              hipStream_t stream)
{
  const float* H    = (const float*)d_in[0];
  const float* Wq   = (const float*)d_in[1];
  const float* Wk   = (const float*)d_in[2];
  const float* Wv   = (const float*)d_in[3];
  const float* Wo   = (const float*)d_in[4];
  const float* Wil  = (const float*)d_in[5];
  const float* bil  = (const float*)d_in[6];
  const float* W1   = (const float*)d_in[7];
  const float* W2   = (const float*)d_in[8];
  float* out        = (float*)d_out;

  float* ws    = (float*)d_ws;
  float* bXC   = ws;
  float* bXB   = ws + 16777216;
  float* bZ2b  = ws + 33554432;
  float* bCo   = ws + 50331648;
  float* bXA   = out;

  unsigned short* hHi = (unsigned short*)bZ2b;
  unsigned short* hLo = hHi + 16777216;
  unsigned short* zHi = (unsigned short*)bXC;
  unsigned short* zLo = zHi + 16777216;

  const int M = Bsz * Lsz, N = Csz, K = Csz;
  dim3 gm(N / 128, M / 128);
  dim3 bm(256);

  split32<<<16384, 256, 0, stream>>>(H, hHi, hLo);
  gemm_mfma<<<gm, bm, 0, stream>>>(hHi, hLo, Wq, bXC, M, N, K);
  gemm_mfma<<<gm, bm, 0, stream>>>(hHi, hLo, Wk, bXB, M, N, K);
  gemm_mfma<<<gm, bm, 0, stream>>>(hHi, hLo, Wv, bXA, M, N, K);
  ilr_coeff<<<M / 4, 256, 0, stream>>>(H, Wil, bil, bCo);
  ttt_scan<<<Bsz * NHsz, 512, 0, stream>>>(bXA, bXB, bXC, bCo, W1, W2, bZ2b);
  split32<<<16384, 256, 0, stream>>>(bZ2b, zHi, zLo);
  gemm_mfma<<<gm, bm, 0, stream>>>(zHi, zLo, Wo, out, M, N, K);
}